// Round 16
// baseline (242.218 us; speedup 1.0000x reference)
//
#include <hip/hip_runtime.h>

typedef __attribute__((ext_vector_type(8))) short bf16x8;
typedef __attribute__((ext_vector_type(4))) float f32x4;
typedef __attribute__((ext_vector_type(2))) float f32x2;
typedef __attribute__((ext_vector_type(2))) unsigned u32x2;
typedef __attribute__((ext_vector_type(4))) unsigned u32x4;

#define N_NODES 50000
#define N_EDGES 800000
#define DIM 128
#define N_GRAPHS 128
#define N_CLASSES 10
#define BN_EPS 1e-5f
#define FBLK ((N_NODES + 63) / 64)        // 782 row tiles
#define FGRID (FBLK / 2)                  // 391 blocks, 2 tiles each
#define NPART (FBLK * 4)                  // 3128 stat-partial rows
#define RED_NB 64
#define RED_ROWS ((NPART + RED_NB - 1) / RED_NB)   // 49

#define NBUCK 196                         // dst buckets of 256 nodes
#define FILL_NB 400
#define FILL_PER (N_EDGES / FILL_NB)      // 2000
#define BMAX 6144                         // max bucket size

#define CVT_NB (N_NODES * 64 / 256)       // 12500
#define PREPW_NB 256

static __device__ __forceinline__ unsigned short f2bf(float f) {
    unsigned u = __float_as_uint(f);
    u += 0x7FFF + ((u >> 16) & 1);   // round-to-nearest-even
    return (unsigned short)(u >> 16);
}
static __device__ __forceinline__ float bf_lo(unsigned u) { return __uint_as_float(u << 16); }
static __device__ __forceinline__ float bf_hi(unsigned u) { return __uint_as_float(u & 0xffff0000u); }
static __device__ __forceinline__ unsigned packbf(float a, float b) {
    return (unsigned)f2bf(a) | ((unsigned)f2bf(b) << 16);
}

// ---- fused prep: x->bf16 | W permute | bucket_count (+last-block scan) | graph starts ----
__global__ __launch_bounds__(256) void prep_all(const f32x2* __restrict__ x,
                                                unsigned* __restrict__ xb,
                                                const float* __restrict__ W0,
                                                const float* __restrict__ W1,
                                                const float* __restrict__ W2,
                                                const float* __restrict__ W3,
                                                unsigned short* __restrict__ wf,
                                                const int* __restrict__ batch,
                                                int* __restrict__ gs,
                                                const int* __restrict__ ei,
                                                int* __restrict__ gbcnt,
                                                int* __restrict__ boff,
                                                int* __restrict__ gcur,
                                                int* __restrict__ ctr_scan) {
    int b = blockIdx.x, tid = threadIdx.x;
    if (b < CVT_NB) {
        int t = b * 256 + tid;
        f32x2 v = x[t];
        xb[t] = packbf(v[0], v[1]);
    } else if (b < CVT_NB + PREPW_NB) {
        int t = (b - CVT_NB) * 256 + tid;
        int m = t >> 14, rem = t & 16383;
        int e = rem & 7, lane = (rem >> 3) & 63, fi = rem >> 9;
        int ks = fi & 3, n = fi >> 2;
        int col = n * 16 + (lane & 15);
        int k = ks * 32 + ((lane >> 4) << 3) + e;
        const float* W = (m == 0) ? W0 : (m == 1) ? W1 : (m == 2) ? W2 : W3;
        wf[t] = f2bf(W[k * DIM + col]);
    } else if (b < CVT_NB + PREPW_NB + FILL_NB) {
        __shared__ int cnt[NBUCK];
        __shared__ int done;
        if (tid < NBUCK) cnt[tid] = 0;
        __syncthreads();
        int e0 = (b - CVT_NB - PREPW_NB) * FILL_PER;
        for (int c = tid; c < FILL_PER; c += 256) {
            int dst = ei[N_EDGES + e0 + c];
            atomicAdd(&cnt[dst >> 8], 1);
        }
        __syncthreads();
        if (tid < NBUCK) atomicAdd(&gbcnt[tid], cnt[tid]);
        __threadfence();
        __syncthreads();
        if (tid == 0) done = atomicAdd(ctr_scan, 1);
        __syncthreads();
        if (done == FILL_NB - 1) {   // last count-block: do the 196-entry scan
            __threadfence();
            __shared__ int buf[256];
            int v = (tid < NBUCK) ? gbcnt[tid] : 0;
            buf[tid] = v;
            __syncthreads();
#pragma unroll
            for (int off = 1; off < 256; off <<= 1) {
                int u = (tid >= off) ? buf[tid - off] : 0;
                __syncthreads();
                buf[tid] += u;
                __syncthreads();
            }
            if (tid < NBUCK) { int ex = buf[tid] - v; boff[tid] = ex; gcur[tid] = ex; }
            if (tid == 0) boff[NBUCK] = N_EDGES;
        }
    } else {
        int g = tid;
        if (g > N_GRAPHS) return;
        int lo = 0, hi = N_NODES;
        while (lo < hi) {
            int mid = (lo + hi) >> 1;
            if (batch[mid] < g) lo = mid + 1; else hi = mid;
        }
        gs[g] = lo;
    }
}

// ---- CSR build stage 3: block-local counting sort by bucket ----
__global__ __launch_bounds__(256) void bucket_fill(const int* __restrict__ ei,
                                                   int* __restrict__ gcur,
                                                   unsigned* __restrict__ gbuf) {
    __shared__ unsigned ent[FILL_PER];
    __shared__ unsigned srt[FILL_PER];
    __shared__ int cnt[256], c2[256], lofs[256], gbase[256];
    int tid = threadIdx.x;
    int e0 = blockIdx.x * FILL_PER;
    cnt[tid] = 0; c2[tid] = 0;
    __syncthreads();
    for (int i = tid; i < FILL_PER; i += 256) {
        int src = ei[e0 + i];
        int dst = ei[N_EDGES + e0 + i];
        ent[i] = (unsigned)src | ((unsigned)(dst & 255) << 16) | ((unsigned)(dst >> 8) << 24);
        atomicAdd(&cnt[dst >> 8], 1);
    }
    __syncthreads();
    int v = cnt[tid];
    lofs[tid] = v;
    __syncthreads();
#pragma unroll
    for (int off = 1; off < 256; off <<= 1) {
        int u = (tid >= off) ? lofs[tid - off] : 0;
        __syncthreads();
        lofs[tid] += u;
        __syncthreads();
    }
    int excl = lofs[tid] - v;
    lofs[tid] = excl;
    if (tid < NBUCK && v > 0) gbase[tid] = atomicAdd(&gcur[tid], v);
    __syncthreads();
    for (int i = tid; i < FILL_PER; i += 256) {
        unsigned w = ent[i];
        int b = w >> 24;
        int r = atomicAdd(&c2[b], 1);
        srt[lofs[b] + r] = w;
    }
    __syncthreads();
    for (int i = tid; i < FILL_PER; i += 256) {
        unsigned w = srt[i];
        int b = w >> 24;
        gbuf[gbase[b] + (i - lofs[b])] = w;
    }
}

// ---- CSR build stage 4: per-bucket in-LDS sort -> row_start + ushort csr ----
__global__ __launch_bounds__(256) void csr_build(const unsigned* __restrict__ gbuf,
                                                 const int* __restrict__ boff,
                                                 unsigned short* __restrict__ csr16,
                                                 int* __restrict__ row_start) {
    __shared__ unsigned ent[BMAX];
    __shared__ unsigned short csl[BMAX];
    __shared__ int cnt[256], c2[256], offs[256];
    int b = blockIdx.x, t = threadIdx.x;
    int base = boff[b], n = boff[b + 1] - base;
    for (int i = t; i < n; i += 256) ent[i] = gbuf[base + i];
    cnt[t] = 0; c2[t] = 0;
    __syncthreads();
    for (int i = t; i < n; i += 256) atomicAdd(&cnt[(ent[i] >> 16) & 255], 1);
    __syncthreads();
    int v = cnt[t];
    offs[t] = v;
    __syncthreads();
#pragma unroll
    for (int off = 1; off < 256; off <<= 1) {
        int u = (t >= off) ? offs[t - off] : 0;
        __syncthreads();
        offs[t] += u;
        __syncthreads();
    }
    int excl = offs[t] - v;
    int node = b * 256 + t;
    if (node < N_NODES) row_start[node] = base + excl;
    if (b == NBUCK - 1 && t == 0) row_start[N_NODES] = N_EDGES;
    __syncthreads();
    offs[t] = excl;
    __syncthreads();
    for (int i = t; i < n; i += 256) {
        unsigned w = ent[i];
        int d = (w >> 16) & 255;
        int r = atomicAdd(&c2[d], 1);
        csl[offs[d] + r] = (unsigned short)(w & 0xffffu);
    }
    __syncthreads();
    for (int i = t; i < n; i += 256) csr16[base + i] = csl[i];
}

// ---- gather-sum aggregation: 16B/lane quarter-wave groups, uniform loop, safe shfl ----
// wave = 1 node; 4 groups of 16 lanes; each group covers the full 256B row (lane u32x4)
// and processes 2 edges per iteration (8 edges/wave-iter).
template <bool BN>
__global__ __launch_bounds__(256) void aggregate_bf(const u32x4* __restrict__ F4,
                                                    u32x4* __restrict__ out,
                                                    const int* __restrict__ row_start,
                                                    const unsigned short* __restrict__ csr16,
                                                    const float* __restrict__ scale,
                                                    const float* __restrict__ shift) {
    int wave = threadIdx.x >> 6, lane = threadIdx.x & 63;
    int v = blockIdx.x * 4 + wave;
    if (v >= N_NODES) return;
    int q = lane >> 4;       // group 0..3
    int c8 = lane & 15;      // 16B chunk (8 cols) within row
    f32x4 scA, scB, shA, shB;
    if (BN) {
        scA = ((const f32x4*)scale)[c8 * 2];
        scB = ((const f32x4*)scale)[c8 * 2 + 1];
        shA = ((const f32x4*)shift)[c8 * 2];
        shB = ((const f32x4*)shift)[c8 * 2 + 1];
    }
    int e0 = row_start[v];
    int n = row_start[v + 1] - e0;
    int myidx = (lane < n) ? (int)csr16[e0 + lane] : 0;   // coalesced 2B/lane, 64 edges
    int n64 = (n < 64) ? n : 64;   // wave-uniform

    float a[8] = {0.f, 0.f, 0.f, 0.f, 0.f, 0.f, 0.f, 0.f};
    float bacc[8] = {0.f, 0.f, 0.f, 0.f, 0.f, 0.f, 0.f, 0.f};

#define UNPACK8(U, P)                                                         \
    P[0] = bf_lo(U[0]); P[1] = bf_hi(U[0]); P[2] = bf_lo(U[1]); P[3] = bf_hi(U[1]); \
    P[4] = bf_lo(U[2]); P[5] = bf_hi(U[2]); P[6] = bf_lo(U[3]); P[7] = bf_hi(U[3]);
#define BN8(P)                                                                \
    if (BN) {                                                                 \
        P[0] = fmaxf(P[0] * scA[0] + shA[0], 0.f);                            \
        P[1] = fmaxf(P[1] * scA[1] + shA[1], 0.f);                            \
        P[2] = fmaxf(P[2] * scA[2] + shA[2], 0.f);                            \
        P[3] = fmaxf(P[3] * scA[3] + shA[3], 0.f);                            \
        P[4] = fmaxf(P[4] * scB[0] + shB[0], 0.f);                            \
        P[5] = fmaxf(P[5] * scB[1] + shB[1], 0.f);                            \
        P[6] = fmaxf(P[6] * scB[2] + shB[2], 0.f);                            \
        P[7] = fmaxf(P[7] * scB[3] + shB[3], 0.f);                            \
    }

    if (q == 0) {   // self term (group 0 only; counted once after combine)
        u32x4 u = F4[(size_t)v * 16 + c8];
        float p[8];
        UNPACK8(u, p)
        BN8(p)
#pragma unroll
        for (int k = 0; k < 8; ++k) a[k] += p[k];
    }

    for (int base = 0; base < n64; base += 8) {   // uniform trip count: shfl is safe
        int j0 = base + q, j1 = base + 4 + q;
        int s0 = __shfl(myidx, j0 & 63, 64);
        int s1 = __shfl(myidx, j1 & 63, 64);
        u32x4 ua = F4[(size_t)s0 * 16 + c8];
        u32x4 ub = F4[(size_t)s1 * 16 + c8];
        float p[8], r[8];
        UNPACK8(ua, p)
        UNPACK8(ub, r)
        BN8(p)
        BN8(r)
        if (j0 < n64) {
#pragma unroll
            for (int k = 0; k < 8; ++k) a[k] += p[k];
        }
        if (j1 < n64) {
#pragma unroll
            for (int k = 0; k < 8; ++k) bacc[k] += r[k];
        }
    }
    for (int j = 64 + q; j < n; j += 4) {   // rare deg>64 tail: direct loads, no shfl
        int s = csr16[e0 + j];
        u32x4 ua = F4[(size_t)s * 16 + c8];
        float p[8];
        UNPACK8(ua, p)
        BN8(p)
#pragma unroll
        for (int k = 0; k < 8; ++k) a[k] += p[k];
    }
#pragma unroll
    for (int k = 0; k < 8; ++k) a[k] += bacc[k];
    // combine the 4 groups (same columns, disjoint edges)
#pragma unroll
    for (int k = 0; k < 8; ++k) {
        a[k] += __shfl_xor(a[k], 16, 64);
        a[k] += __shfl_xor(a[k], 32, 64);
    }
    if (q == 0) {
        u32x4 w;
        w[0] = packbf(a[0], a[1]);
        w[1] = packbf(a[2], a[3]);
        w[2] = packbf(a[4], a[5]);
        w[3] = packbf(a[6], a[7]);
        out[(size_t)v * 16 + c8] = w;
    }
#undef UNPACK8
#undef BN8
}

// ---- fused GIN layer: 2 row-tiles per block; Wa+Wb in regs, staged per phase ----
__global__ __launch_bounds__(256, 3) void fused_layer(
        const unsigned short* __restrict__ A,
        const bf16x8* __restrict__ wfA_g,
        const bf16x8* __restrict__ wfB_g,
        const float* __restrict__ bias_a,
        const float* __restrict__ bias_b,
        unsigned short* __restrict__ out,
        float* __restrict__ psum,
        float* __restrict__ psq, int M) {
    __shared__ bf16x8 wfS[2048];
    __shared__ unsigned short mid[8192];

    int tid = threadIdx.x;
    int w = tid >> 6, lane = tid & 63;
    int cl = lane & 15, kq = lane >> 4;

    bf16x8 wa[8], wb[8];
#pragma unroll
    for (int i = 0; i < 8; ++i) wa[i] = wfA_g[i * 256 + tid];
#pragma unroll
    for (int i = 0; i < 8; ++i) wb[i] = wfB_g[i * 256 + tid];

    for (int t = 0; t < 2; ++t) {
        int tile = blockIdx.x + t * FGRID;
        int rblk = tile * 64;

#pragma unroll
        for (int i = 0; i < 8; ++i) wfS[i * 256 + tid] = wa[i];

        int arow = rblk + w * 16 + cl;
        if (arow >= M) arow = M - 1;
        bf16x8 af[4];
        const unsigned short* Ap = A + (size_t)arow * DIM + kq * 8;
#pragma unroll
        for (int ks = 0; ks < 4; ++ks) af[ks] = *(const bf16x8*)(Ap + ks * 32);

        __syncthreads();

        f32x4 acc[8];
#pragma unroll
        for (int n = 0; n < 8; ++n) acc[n] = f32x4{0.f, 0.f, 0.f, 0.f};
#pragma unroll
        for (int n = 0; n < 8; ++n)
#pragma unroll
            for (int ks = 0; ks < 4; ++ks)
                acc[n] = __builtin_amdgcn_mfma_f32_16x16x32_bf16(
                    af[ks], wfS[(n * 4 + ks) * 64 + lane], acc[n], 0, 0, 0);

#pragma unroll
        for (int n = 0; n < 8; ++n) {
            int col = n * 16 + cl;
            float b = bias_a[col];
#pragma unroll
            for (int r = 0; r < 4; ++r) {
                int rl = w * 16 + kq * 4 + r;
                float v = fmaxf(acc[n][r] + b, 0.f);
                mid[(rl * DIM + col) ^ ((rl & 7) << 3)] = f2bf(v);
            }
        }
        __syncthreads();

#pragma unroll
        for (int i = 0; i < 8; ++i) wfS[i * 256 + tid] = wb[i];

        bf16x8 af2[4];
        {
            int rl = w * 16 + cl;
            int sw = (cl & 7) << 3;
#pragma unroll
            for (int ks = 0; ks < 4; ++ks)
                af2[ks] = *(const bf16x8*)(mid + ((rl * DIM + kq * 8 + ks * 32) ^ sw));
        }
        __syncthreads();

        f32x4 acc2[8];
#pragma unroll
        for (int n = 0; n < 8; ++n) acc2[n] = f32x4{0.f, 0.f, 0.f, 0.f};
#pragma unroll
        for (int n = 0; n < 8; ++n)
#pragma unroll
            for (int ks = 0; ks < 4; ++ks)
                acc2[n] = __builtin_amdgcn_mfma_f32_16x16x32_bf16(
                    af2[ks], wfS[(n * 4 + ks) * 64 + lane], acc2[n], 0, 0, 0);

        int prow = tile * 4 + w;
#pragma unroll
        for (int n = 0; n < 8; ++n) {
            int col = n * 16 + cl;
            float b = bias_b[col];
            float s = 0.f, q = 0.f;
#pragma unroll
            for (int r = 0; r < 4; ++r) {
                int rl = w * 16 + kq * 4 + r;
                float v = acc2[n][r] + b;
                if (rblk + rl < M) { s += v; q += v * v; }
                mid[(rl * DIM + col) ^ ((rl & 7) << 3)] = f2bf(v);
            }
            s += __shfl_xor(s, 16, 64);
            s += __shfl_xor(s, 32, 64);
            q += __shfl_xor(q, 16, 64);
            q += __shfl_xor(q, 32, 64);
            if (kq == 0) {
                psum[(size_t)prow * DIM + col] = s;
                psq[(size_t)prow * DIM + col] = q;
            }
        }

        {
            int r4 = lane >> 4, c = lane & 15;
#pragma unroll
            for (int rb = 0; rb < 4; ++rb) {
                int rl = w * 16 + rb * 4 + r4;
                int grow = rblk + rl;
                bf16x8 v = *(const bf16x8*)(mid + ((rl * DIM + c * 8) ^ ((rl & 7) << 3)));
                if (grow < M) *(bf16x8*)(out + (size_t)grow * DIM + c * 8) = v;
            }
        }
        __syncthreads();
    }
}

// ---- stats: stage-1 reduce (64 blocks) + last-block finalize (scale/shift) ----
__global__ __launch_bounds__(256) void stats_all(const float* __restrict__ psum,
                                                 const float* __restrict__ psq,
                                                 float* __restrict__ ps2,
                                                 const float* __restrict__ g,
                                                 const float* __restrict__ be,
                                                 float* __restrict__ scale,
                                                 float* __restrict__ shift,
                                                 int* __restrict__ ctr) {
    int b = blockIdx.x, t = threadIdx.x;
    int c = t & 127;
    const float* src = (t < 128) ? psum : psq;
    int r0 = b * RED_ROWS;
    int r1 = min(NPART, r0 + RED_ROWS);
    float acc = 0.f;
    for (int r = r0; r < r1; ++r) acc += src[(size_t)r * DIM + c];
    ps2[(size_t)b * 256 + t] = acc;
    __threadfence();
    __shared__ int done;
    __syncthreads();
    if (t == 0) done = atomicAdd(ctr, 1);
    __syncthreads();
    if (done == RED_NB - 1) {   // last block finalizes
        __threadfence();
        float a2 = 0.f;
#pragma unroll 4
        for (int r = 0; r < RED_NB; ++r) a2 += ps2[(size_t)r * 256 + t];
        __shared__ float sums[128], sqs[128];
        if (t < 128) sums[c] = a2; else sqs[c] = a2;
        __syncthreads();
        if (t < 128) {
            const float invN = 1.0f / (float)N_NODES;
            float mu = sums[c] * invN;
            float var = sqs[c] * invN - mu * mu;
            float rs = rsqrtf(var + BN_EPS) * g[c];
            scale[c] = rs;
            shift[c] = be[c] - mu * rs;
        }
    }
}

// ---- BN apply + ReLU + segmented pool + classifier (one block per graph) ----
__global__ __launch_bounds__(256) void bn_pool_final(const unsigned short* __restrict__ h,
                                                     const float* __restrict__ scale,
                                                     const float* __restrict__ shift,
                                                     const int* __restrict__ gs,
                                                     const float* __restrict__ Wo,
                                                     const float* __restrict__ bo,
                                                     float* __restrict__ out) {
    int g = blockIdx.x;
    int t = threadIdx.x;
    int c4 = t & 31;
    int rs = t >> 5;
    int r0 = gs[g], r1 = gs[g + 1];
    f32x4 sc = ((const f32x4*)scale)[c4];
    f32x4 sh = ((const f32x4*)shift)[c4];
    f32x4 acc = f32x4{0.f, 0.f, 0.f, 0.f};
    for (int r = r0 + rs; r < r1; r += 8) {
        u32x2 u = *(const u32x2*)(h + (size_t)r * DIM + c4 * 4);
        float f0 = bf_lo(u[0]), f1 = bf_hi(u[0]), f2 = bf_lo(u[1]), f3 = bf_hi(u[1]);
        acc[0] += fmaxf(f0 * sc[0] + sh[0], 0.f);
        acc[1] += fmaxf(f1 * sc[1] + sh[1], 0.f);
        acc[2] += fmaxf(f2 * sc[2] + sh[2], 0.f);
        acc[3] += fmaxf(f3 * sc[3] + sh[3], 0.f);
    }
    __shared__ f32x4 red[256];
    __shared__ float pf[DIM];
    red[t] = acc;
    __syncthreads();
#pragma unroll
    for (int off = 128; off >= 32; off >>= 1) {
        if (t < off) red[t] += red[t + off];
        __syncthreads();
    }
    if (t < 32) {
        f32x4 r = red[t];
        pf[t * 4 + 0] = r[0]; pf[t * 4 + 1] = r[1];
        pf[t * 4 + 2] = r[2]; pf[t * 4 + 3] = r[3];
    }
    __syncthreads();
    if (t < N_CLASSES) {
        float s = bo[t];
#pragma unroll 8
        for (int k = 0; k < DIM; ++k) s += pf[k] * Wo[k * N_CLASSES + t];
        out[g * N_CLASSES + t] = s;
    }
}

extern "C" void kernel_launch(void* const* d_in, const int* in_sizes, int n_in,
                              void* d_out, int out_size, void* d_ws, size_t ws_size,
                              hipStream_t stream) {
    const float* x   = (const float*)d_in[0];
    const int* ei    = (const int*)d_in[1];   // harness: integer -> int32
    const int* batch = (const int*)d_in[2];
    const float* W1a = (const float*)d_in[3];
    const float* b1a = (const float*)d_in[4];
    const float* W1b = (const float*)d_in[5];
    const float* b1b = (const float*)d_in[6];
    const float* g1  = (const float*)d_in[7];
    const float* be1 = (const float*)d_in[8];
    const float* W2a = (const float*)d_in[9];
    const float* b2a = (const float*)d_in[10];
    const float* W2b = (const float*)d_in[11];
    const float* b2b = (const float*)d_in[12];
    const float* g2  = (const float*)d_in[13];
    const float* be2 = (const float*)d_in[14];
    const float* Wo  = (const float*)d_in[15];
    const float* bo  = (const float*)d_in[16];

    char* ws = (char*)d_ws;
    const size_t NBH = (size_t)N_NODES * DIM * 2;   // 12.8 MB bf16 features
    unsigned short* xb   = (unsigned short*)ws;
    unsigned short* aggb = (unsigned short*)(ws + NBH);
    unsigned short* hb   = (unsigned short*)(ws + 2 * NBH);
    unsigned short* wfrag = (unsigned short*)(ws + 3 * NBH);   // 128 KB
    float* psum = (float*)(ws + 3 * NBH + 4 * 16384 * 2);      // NPART*128
    float* psq  = psum + (size_t)NPART * DIM;
    float* ps2  = psq + (size_t)NPART * DIM;       // RED_NB*256
    float* scale1  = ps2 + RED_NB * 256;
    float* shift1  = scale1 + 128;
    float* scale2  = scale1 + 256;
    float* shift2  = scale1 + 384;
    int* gs        = (int*)(shift2 + 128);         // N_GRAPHS+1
    int* gbcnt     = gs + N_GRAPHS + 1;            // NBUCK
    int* ctrs      = gbcnt + NBUCK;                // 3 counters (scan, stats1, stats2)
    int* boff      = ctrs + 3;                     // NBUCK+1
    int* gcur      = boff + NBUCK + 1;             // NBUCK
    int* row_start = gcur + NBUCK;                 // N_NODES+1
    unsigned* gbuf = (unsigned*)(row_start + N_NODES + 1);     // N_EDGES u32
    unsigned short* csr16 = (unsigned short*)(gbuf + N_EDGES); // N_EDGES ushort

    hipMemsetAsync(gbcnt, 0, (NBUCK + 3) * 4, stream);   // gbcnt + 3 counters

    prep_all<<<CVT_NB + PREPW_NB + FILL_NB + 1, 256, 0, stream>>>(
        (const f32x2*)x, (unsigned*)xb, W1a, W1b, W2a, W2b, wfrag, batch, gs, ei,
        gbcnt, boff, gcur, ctrs + 0);

    bucket_fill<<<FILL_NB, 256, 0, stream>>>(ei, gcur, gbuf);
    csr_build<<<NBUCK, 256, 0, stream>>>(gbuf, boff, csr16, row_start);

    const int ablk = (N_NODES + 3) / 4;

    // layer 1
    aggregate_bf<false><<<ablk, 256, 0, stream>>>((const u32x4*)xb, (u32x4*)aggb,
                                                  row_start, csr16, nullptr, nullptr);
    fused_layer<<<FGRID, 256, 0, stream>>>(
        aggb, (const bf16x8*)(wfrag + 0 * 16384), (const bf16x8*)(wfrag + 1 * 16384),
        b1a, b1b, hb, psum, psq, N_NODES);
    stats_all<<<RED_NB, 256, 0, stream>>>(psum, psq, ps2, g1, be1, scale1, shift1,
                                          ctrs + 1);

    // layer 2 (BN1+ReLU fused into aggregate)
    aggregate_bf<true><<<ablk, 256, 0, stream>>>((const u32x4*)hb, (u32x4*)aggb,
                                                 row_start, csr16, scale1, shift1);
    fused_layer<<<FGRID, 256, 0, stream>>>(
        aggb, (const bf16x8*)(wfrag + 2 * 16384), (const bf16x8*)(wfrag + 3 * 16384),
        b2a, b2b, hb, psum, psq, N_NODES);
    stats_all<<<RED_NB, 256, 0, stream>>>(psum, psq, ps2, g2, be2, scale2, shift2,
                                          ctrs + 2);

    bn_pool_final<<<N_GRAPHS, 256, 0, stream>>>(hb, scale2, shift2, gs, Wo, bo,
                                                (float*)d_out);
}

// Round 17
// 226.986 us; speedup vs baseline: 1.0671x; 1.0671x over previous
//
#include <hip/hip_runtime.h>

typedef __attribute__((ext_vector_type(8))) short bf16x8;
typedef __attribute__((ext_vector_type(4))) float f32x4;
typedef __attribute__((ext_vector_type(2))) float f32x2;
typedef __attribute__((ext_vector_type(2))) unsigned u32x2;
typedef __attribute__((ext_vector_type(4))) unsigned u32x4;

#define N_NODES 50000
#define N_EDGES 800000
#define DIM 128
#define N_GRAPHS 128
#define N_CLASSES 10
#define BN_EPS 1e-5f
#define FBLK ((N_NODES + 63) / 64)        // 782 row tiles
#define FGRID (FBLK / 2)                  // 391 blocks, 2 tiles each
#define NPART (FBLK * 4)                  // 3128 stat-partial rows
#define RED_NB 64
#define RED_ROWS ((NPART + RED_NB - 1) / RED_NB)   // 49

#define NBUCK 196                         // dst buckets of 256 nodes
#define FILL_NB 400
#define FILL_PER (N_EDGES / FILL_NB)      // 2000
#define BMAX 6144                         // max bucket size

#define CVT_NB (N_NODES * 64 / 256)       // 12500
#define PREPW_NB 256

static __device__ __forceinline__ unsigned short f2bf(float f) {
    unsigned u = __float_as_uint(f);
    u += 0x7FFF + ((u >> 16) & 1);   // round-to-nearest-even
    return (unsigned short)(u >> 16);
}
static __device__ __forceinline__ float bf_lo(unsigned u) { return __uint_as_float(u << 16); }
static __device__ __forceinline__ float bf_hi(unsigned u) { return __uint_as_float(u & 0xffff0000u); }
static __device__ __forceinline__ unsigned packbf(float a, float b) {
    return (unsigned)f2bf(a) | ((unsigned)f2bf(b) << 16);
}

// ---- fused prep: x->bf16 | W permute | bucket_count | graph starts (NO fences) ----
__global__ __launch_bounds__(256) void prep_all(const f32x2* __restrict__ x,
                                                unsigned* __restrict__ xb,
                                                const float* __restrict__ W0,
                                                const float* __restrict__ W1,
                                                const float* __restrict__ W2,
                                                const float* __restrict__ W3,
                                                unsigned short* __restrict__ wf,
                                                const int* __restrict__ batch,
                                                int* __restrict__ gs,
                                                const int* __restrict__ ei,
                                                int* __restrict__ gbcnt) {
    int b = blockIdx.x, tid = threadIdx.x;
    if (b < CVT_NB) {
        int t = b * 256 + tid;
        f32x2 v = x[t];
        xb[t] = packbf(v[0], v[1]);
    } else if (b < CVT_NB + PREPW_NB) {
        int t = (b - CVT_NB) * 256 + tid;
        int m = t >> 14, rem = t & 16383;
        int e = rem & 7, lane = (rem >> 3) & 63, fi = rem >> 9;
        int ks = fi & 3, n = fi >> 2;
        int col = n * 16 + (lane & 15);
        int k = ks * 32 + ((lane >> 4) << 3) + e;
        const float* W = (m == 0) ? W0 : (m == 1) ? W1 : (m == 2) ? W2 : W3;
        wf[t] = f2bf(W[k * DIM + col]);
    } else if (b < CVT_NB + PREPW_NB + FILL_NB) {
        __shared__ int cnt[NBUCK];
        if (tid < NBUCK) cnt[tid] = 0;
        __syncthreads();
        int e0 = (b - CVT_NB - PREPW_NB) * FILL_PER;
        for (int c = tid; c < FILL_PER; c += 256) {
            int dst = ei[N_EDGES + e0 + c];
            atomicAdd(&cnt[dst >> 8], 1);
        }
        __syncthreads();
        if (tid < NBUCK) atomicAdd(&gbcnt[tid], cnt[tid]);
    } else {
        int g = tid;
        if (g > N_GRAPHS) return;
        int lo = 0, hi = N_NODES;
        while (lo < hi) {
            int mid = (lo + hi) >> 1;
            if (batch[mid] < g) lo = mid + 1; else hi = mid;
        }
        gs[g] = lo;
    }
}

// ---- CSR build stage 2: scan 196 bucket counts; init cursors ----
__global__ __launch_bounds__(256) void bucket_scan(const int* __restrict__ gbcnt,
                                                   int* __restrict__ boff,
                                                   int* __restrict__ gcur) {
    __shared__ int buf[256];
    int t = threadIdx.x;
    int v = (t < NBUCK) ? gbcnt[t] : 0;
    buf[t] = v;
    __syncthreads();
#pragma unroll
    for (int off = 1; off < 256; off <<= 1) {
        int u = (t >= off) ? buf[t - off] : 0;
        __syncthreads();
        buf[t] += u;
        __syncthreads();
    }
    if (t < NBUCK) { int ex = buf[t] - v; boff[t] = ex; gcur[t] = ex; }
    if (t == 0) boff[NBUCK] = N_EDGES;
}

// ---- CSR build stage 3: block-local counting sort by bucket ----
__global__ __launch_bounds__(256) void bucket_fill(const int* __restrict__ ei,
                                                   int* __restrict__ gcur,
                                                   unsigned* __restrict__ gbuf) {
    __shared__ unsigned ent[FILL_PER];
    __shared__ unsigned srt[FILL_PER];
    __shared__ int cnt[256], c2[256], lofs[256], gbase[256];
    int tid = threadIdx.x;
    int e0 = blockIdx.x * FILL_PER;
    cnt[tid] = 0; c2[tid] = 0;
    __syncthreads();
    for (int i = tid; i < FILL_PER; i += 256) {
        int src = ei[e0 + i];
        int dst = ei[N_EDGES + e0 + i];
        ent[i] = (unsigned)src | ((unsigned)(dst & 255) << 16) | ((unsigned)(dst >> 8) << 24);
        atomicAdd(&cnt[dst >> 8], 1);
    }
    __syncthreads();
    int v = cnt[tid];
    lofs[tid] = v;
    __syncthreads();
#pragma unroll
    for (int off = 1; off < 256; off <<= 1) {
        int u = (tid >= off) ? lofs[tid - off] : 0;
        __syncthreads();
        lofs[tid] += u;
        __syncthreads();
    }
    int excl = lofs[tid] - v;
    lofs[tid] = excl;
    if (tid < NBUCK && v > 0) gbase[tid] = atomicAdd(&gcur[tid], v);
    __syncthreads();
    for (int i = tid; i < FILL_PER; i += 256) {
        unsigned w = ent[i];
        int b = w >> 24;
        int r = atomicAdd(&c2[b], 1);
        srt[lofs[b] + r] = w;
    }
    __syncthreads();
    for (int i = tid; i < FILL_PER; i += 256) {
        unsigned w = srt[i];
        int b = w >> 24;
        gbuf[gbase[b] + (i - lofs[b])] = w;
    }
}

// ---- CSR build stage 4: per-bucket in-LDS sort -> row_start + ushort csr ----
__global__ __launch_bounds__(256) void csr_build(const unsigned* __restrict__ gbuf,
                                                 const int* __restrict__ boff,
                                                 unsigned short* __restrict__ csr16,
                                                 int* __restrict__ row_start) {
    __shared__ unsigned ent[BMAX];
    __shared__ unsigned short csl[BMAX];
    __shared__ int cnt[256], c2[256], offs[256];
    int b = blockIdx.x, t = threadIdx.x;
    int base = boff[b], n = boff[b + 1] - base;
    for (int i = t; i < n; i += 256) ent[i] = gbuf[base + i];
    cnt[t] = 0; c2[t] = 0;
    __syncthreads();
    for (int i = t; i < n; i += 256) atomicAdd(&cnt[(ent[i] >> 16) & 255], 1);
    __syncthreads();
    int v = cnt[t];
    offs[t] = v;
    __syncthreads();
#pragma unroll
    for (int off = 1; off < 256; off <<= 1) {
        int u = (t >= off) ? offs[t - off] : 0;
        __syncthreads();
        offs[t] += u;
        __syncthreads();
    }
    int excl = offs[t] - v;
    int node = b * 256 + t;
    if (node < N_NODES) row_start[node] = base + excl;
    if (b == NBUCK - 1 && t == 0) row_start[N_NODES] = N_EDGES;
    __syncthreads();
    offs[t] = excl;
    __syncthreads();
    for (int i = t; i < n; i += 256) {
        unsigned w = ent[i];
        int d = (w >> 16) & 255;
        int r = atomicAdd(&c2[d], 1);
        csl[offs[d] + r] = (unsigned short)(w & 0xffffu);
    }
    __syncthreads();
    for (int i = t; i < n; i += 256) csr16[base + i] = csl[i];
}

// ---- gather-sum aggregation: 16B/lane quarter-wave groups + 4-deep MLP ----
// wave = 1 node; 4 groups of 16 lanes; each group covers the full 256B row and
// keeps 4 loads in flight (16 edges/wave-iter). Uniform trip count -> safe shfl.
template <bool BN>
__global__ __launch_bounds__(256) void aggregate_bf(const u32x4* __restrict__ F4,
                                                    u32x4* __restrict__ out,
                                                    const int* __restrict__ row_start,
                                                    const unsigned short* __restrict__ csr16,
                                                    const float* __restrict__ scale,
                                                    const float* __restrict__ shift) {
    int wave = threadIdx.x >> 6, lane = threadIdx.x & 63;
    int v = blockIdx.x * 4 + wave;
    if (v >= N_NODES) return;
    int q = lane >> 4;       // group 0..3
    int c8 = lane & 15;      // 16B chunk (8 cols) within row
    f32x4 scA, scB, shA, shB;
    if (BN) {
        scA = ((const f32x4*)scale)[c8 * 2];
        scB = ((const f32x4*)scale)[c8 * 2 + 1];
        shA = ((const f32x4*)shift)[c8 * 2];
        shB = ((const f32x4*)shift)[c8 * 2 + 1];
    }
    int e0 = row_start[v];
    int n = row_start[v + 1] - e0;
    int myidx = (lane < n) ? (int)csr16[e0 + lane] : 0;   // coalesced 2B/lane, 64 edges
    int n64 = (n < 64) ? n : 64;   // wave-uniform

    float a[8] = {0.f, 0.f, 0.f, 0.f, 0.f, 0.f, 0.f, 0.f};
    float b2[8] = {0.f, 0.f, 0.f, 0.f, 0.f, 0.f, 0.f, 0.f};

#define UNPACK8(U, P)                                                         \
    P[0] = bf_lo(U[0]); P[1] = bf_hi(U[0]); P[2] = bf_lo(U[1]); P[3] = bf_hi(U[1]); \
    P[4] = bf_lo(U[2]); P[5] = bf_hi(U[2]); P[6] = bf_lo(U[3]); P[7] = bf_hi(U[3]);
#define BN8(P)                                                                \
    if (BN) {                                                                 \
        P[0] = fmaxf(P[0] * scA[0] + shA[0], 0.f);                            \
        P[1] = fmaxf(P[1] * scA[1] + shA[1], 0.f);                            \
        P[2] = fmaxf(P[2] * scA[2] + shA[2], 0.f);                            \
        P[3] = fmaxf(P[3] * scA[3] + shA[3], 0.f);                            \
        P[4] = fmaxf(P[4] * scB[0] + shB[0], 0.f);                            \
        P[5] = fmaxf(P[5] * scB[1] + shB[1], 0.f);                            \
        P[6] = fmaxf(P[6] * scB[2] + shB[2], 0.f);                            \
        P[7] = fmaxf(P[7] * scB[3] + shB[3], 0.f);                            \
    }

    if (q == 0) {   // self term (group 0 only; counted once after combine)
        u32x4 u = F4[(size_t)v * 16 + c8];
        float p[8];
        UNPACK8(u, p)
        BN8(p)
#pragma unroll
        for (int k = 0; k < 8; ++k) a[k] += p[k];
    }

    for (int base = 0; base < n64; base += 16) {   // uniform trips; 4 loads in flight
        int j0 = base + q, j1 = base + 4 + q, j2 = base + 8 + q, j3 = base + 12 + q;
        int s0 = __shfl(myidx, j0 & 63, 64);
        int s1 = __shfl(myidx, j1 & 63, 64);
        int s2 = __shfl(myidx, j2 & 63, 64);
        int s3 = __shfl(myidx, j3 & 63, 64);
        u32x4 ua = F4[(size_t)s0 * 16 + c8];
        u32x4 ub = F4[(size_t)s1 * 16 + c8];
        u32x4 uc = F4[(size_t)s2 * 16 + c8];
        u32x4 ud = F4[(size_t)s3 * 16 + c8];
        float pa[8], pb[8], pc[8], pd[8];
        UNPACK8(ua, pa)
        UNPACK8(ub, pb)
        UNPACK8(uc, pc)
        UNPACK8(ud, pd)
        BN8(pa)
        BN8(pb)
        BN8(pc)
        BN8(pd)
        if (j0 < n64) {
#pragma unroll
            for (int k = 0; k < 8; ++k) a[k] += pa[k];
        }
        if (j1 < n64) {
#pragma unroll
            for (int k = 0; k < 8; ++k) b2[k] += pb[k];
        }
        if (j2 < n64) {
#pragma unroll
            for (int k = 0; k < 8; ++k) a[k] += pc[k];
        }
        if (j3 < n64) {
#pragma unroll
            for (int k = 0; k < 8; ++k) b2[k] += pd[k];
        }
    }
    for (int j = 64 + q; j < n; j += 4) {   // rare deg>64 tail: direct loads, no shfl
        int s = csr16[e0 + j];
        u32x4 ua = F4[(size_t)s * 16 + c8];
        float p[8];
        UNPACK8(ua, p)
        BN8(p)
#pragma unroll
        for (int k = 0; k < 8; ++k) a[k] += p[k];
    }
#pragma unroll
    for (int k = 0; k < 8; ++k) a[k] += b2[k];
    // combine the 4 groups (same columns, disjoint edges)
#pragma unroll
    for (int k = 0; k < 8; ++k) {
        a[k] += __shfl_xor(a[k], 16, 64);
        a[k] += __shfl_xor(a[k], 32, 64);
    }
    if (q == 0) {
        u32x4 w;
        w[0] = packbf(a[0], a[1]);
        w[1] = packbf(a[2], a[3]);
        w[2] = packbf(a[4], a[5]);
        w[3] = packbf(a[6], a[7]);
        out[(size_t)v * 16 + c8] = w;
    }
#undef UNPACK8
#undef BN8
}

// ---- fused GIN layer: 2 row-tiles per block; Wa+Wb in regs, staged per phase ----
__global__ __launch_bounds__(256, 3) void fused_layer(
        const unsigned short* __restrict__ A,
        const bf16x8* __restrict__ wfA_g,
        const bf16x8* __restrict__ wfB_g,
        const float* __restrict__ bias_a,
        const float* __restrict__ bias_b,
        unsigned short* __restrict__ out,
        float* __restrict__ psum,
        float* __restrict__ psq, int M) {
    __shared__ bf16x8 wfS[2048];
    __shared__ unsigned short mid[8192];

    int tid = threadIdx.x;
    int w = tid >> 6, lane = tid & 63;
    int cl = lane & 15, kq = lane >> 4;

    bf16x8 wa[8], wb[8];
#pragma unroll
    for (int i = 0; i < 8; ++i) wa[i] = wfA_g[i * 256 + tid];
#pragma unroll
    for (int i = 0; i < 8; ++i) wb[i] = wfB_g[i * 256 + tid];

    for (int t = 0; t < 2; ++t) {
        int tile = blockIdx.x + t * FGRID;
        int rblk = tile * 64;

#pragma unroll
        for (int i = 0; i < 8; ++i) wfS[i * 256 + tid] = wa[i];

        int arow = rblk + w * 16 + cl;
        if (arow >= M) arow = M - 1;
        bf16x8 af[4];
        const unsigned short* Ap = A + (size_t)arow * DIM + kq * 8;
#pragma unroll
        for (int ks = 0; ks < 4; ++ks) af[ks] = *(const bf16x8*)(Ap + ks * 32);

        __syncthreads();

        f32x4 acc[8];
#pragma unroll
        for (int n = 0; n < 8; ++n) acc[n] = f32x4{0.f, 0.f, 0.f, 0.f};
#pragma unroll
        for (int n = 0; n < 8; ++n)
#pragma unroll
            for (int ks = 0; ks < 4; ++ks)
                acc[n] = __builtin_amdgcn_mfma_f32_16x16x32_bf16(
                    af[ks], wfS[(n * 4 + ks) * 64 + lane], acc[n], 0, 0, 0);

#pragma unroll
        for (int n = 0; n < 8; ++n) {
            int col = n * 16 + cl;
            float b = bias_a[col];
#pragma unroll
            for (int r = 0; r < 4; ++r) {
                int rl = w * 16 + kq * 4 + r;
                float v = fmaxf(acc[n][r] + b, 0.f);
                mid[(rl * DIM + col) ^ ((rl & 7) << 3)] = f2bf(v);
            }
        }
        __syncthreads();

#pragma unroll
        for (int i = 0; i < 8; ++i) wfS[i * 256 + tid] = wb[i];

        bf16x8 af2[4];
        {
            int rl = w * 16 + cl;
            int sw = (cl & 7) << 3;
#pragma unroll
            for (int ks = 0; ks < 4; ++ks)
                af2[ks] = *(const bf16x8*)(mid + ((rl * DIM + kq * 8 + ks * 32) ^ sw));
        }
        __syncthreads();

        f32x4 acc2[8];
#pragma unroll
        for (int n = 0; n < 8; ++n) acc2[n] = f32x4{0.f, 0.f, 0.f, 0.f};
#pragma unroll
        for (int n = 0; n < 8; ++n)
#pragma unroll
            for (int ks = 0; ks < 4; ++ks)
                acc2[n] = __builtin_amdgcn_mfma_f32_16x16x32_bf16(
                    af2[ks], wfS[(n * 4 + ks) * 64 + lane], acc2[n], 0, 0, 0);

        int prow = tile * 4 + w;
#pragma unroll
        for (int n = 0; n < 8; ++n) {
            int col = n * 16 + cl;
            float b = bias_b[col];
            float s = 0.f, q = 0.f;
#pragma unroll
            for (int r = 0; r < 4; ++r) {
                int rl = w * 16 + kq * 4 + r;
                float v = acc2[n][r] + b;
                if (rblk + rl < M) { s += v; q += v * v; }
                mid[(rl * DIM + col) ^ ((rl & 7) << 3)] = f2bf(v);
            }
            s += __shfl_xor(s, 16, 64);
            s += __shfl_xor(s, 32, 64);
            q += __shfl_xor(q, 16, 64);
            q += __shfl_xor(q, 32, 64);
            if (kq == 0) {
                psum[(size_t)prow * DIM + col] = s;
                psq[(size_t)prow * DIM + col] = q;
            }
        }

        {
            int r4 = lane >> 4, c = lane & 15;
#pragma unroll
            for (int rb = 0; rb < 4; ++rb) {
                int rl = w * 16 + rb * 4 + r4;
                int grow = rblk + rl;
                bf16x8 v = *(const bf16x8*)(mid + ((rl * DIM + c * 8) ^ ((rl & 7) << 3)));
                if (grow < M) *(bf16x8*)(out + (size_t)grow * DIM + c * 8) = v;
            }
        }
        __syncthreads();
    }
}

// ---- stats reduction stage 1 ----
__global__ __launch_bounds__(256) void reduce_stats(const float* __restrict__ psum,
                                                    const float* __restrict__ psq,
                                                    float* __restrict__ ps2) {
    int b = blockIdx.x, t = threadIdx.x;
    int c = t & 127;
    const float* src = (t < 128) ? psum : psq;
    int r0 = b * RED_ROWS;
    int r1 = min(NPART, r0 + RED_ROWS);
    float acc = 0.f;
    for (int r = r0; r < r1; ++r) acc += src[(size_t)r * DIM + c];
    ps2[(size_t)b * 256 + t] = acc;
}

// ---- BN finalize ----
__global__ __launch_bounds__(256) void bn_finalize(const float* __restrict__ ps2,
                                                   const float* __restrict__ g,
                                                   const float* __restrict__ be,
                                                   float* __restrict__ scale,
                                                   float* __restrict__ shift) {
    __shared__ float sums[128], sqs[128];
    int t = threadIdx.x;
    int c = t & 127;
    float acc = 0.f;
#pragma unroll 4
    for (int r = 0; r < RED_NB; ++r) acc += ps2[(size_t)r * 256 + t];
    if (t < 128) sums[c] = acc; else sqs[c] = acc;
    __syncthreads();
    if (t < 128) {
        const float invN = 1.0f / (float)N_NODES;
        float mu = sums[c] * invN;
        float var = sqs[c] * invN - mu * mu;
        float rs = rsqrtf(var + BN_EPS) * g[c];
        scale[c] = rs;
        shift[c] = be[c] - mu * rs;
    }
}

// ---- BN apply + ReLU + segmented pool + classifier (one block per graph) ----
__global__ __launch_bounds__(256) void bn_pool_final(const unsigned short* __restrict__ h,
                                                     const float* __restrict__ scale,
                                                     const float* __restrict__ shift,
                                                     const int* __restrict__ gs,
                                                     const float* __restrict__ Wo,
                                                     const float* __restrict__ bo,
                                                     float* __restrict__ out) {
    int g = blockIdx.x;
    int t = threadIdx.x;
    int c4 = t & 31;
    int rs = t >> 5;
    int r0 = gs[g], r1 = gs[g + 1];
    f32x4 sc = ((const f32x4*)scale)[c4];
    f32x4 sh = ((const f32x4*)shift)[c4];
    f32x4 acc = f32x4{0.f, 0.f, 0.f, 0.f};
    for (int r = r0 + rs; r < r1; r += 8) {
        u32x2 u = *(const u32x2*)(h + (size_t)r * DIM + c4 * 4);
        float f0 = bf_lo(u[0]), f1 = bf_hi(u[0]), f2 = bf_lo(u[1]), f3 = bf_hi(u[1]);
        acc[0] += fmaxf(f0 * sc[0] + sh[0], 0.f);
        acc[1] += fmaxf(f1 * sc[1] + sh[1], 0.f);
        acc[2] += fmaxf(f2 * sc[2] + sh[2], 0.f);
        acc[3] += fmaxf(f3 * sc[3] + sh[3], 0.f);
    }
    __shared__ f32x4 red[256];
    __shared__ float pf[DIM];
    red[t] = acc;
    __syncthreads();
#pragma unroll
    for (int off = 128; off >= 32; off >>= 1) {
        if (t < off) red[t] += red[t + off];
        __syncthreads();
    }
    if (t < 32) {
        f32x4 r = red[t];
        pf[t * 4 + 0] = r[0]; pf[t * 4 + 1] = r[1];
        pf[t * 4 + 2] = r[2]; pf[t * 4 + 3] = r[3];
    }
    __syncthreads();
    if (t < N_CLASSES) {
        float s = bo[t];
#pragma unroll 8
        for (int k = 0; k < DIM; ++k) s += pf[k] * Wo[k * N_CLASSES + t];
        out[g * N_CLASSES + t] = s;
    }
}

extern "C" void kernel_launch(void* const* d_in, const int* in_sizes, int n_in,
                              void* d_out, int out_size, void* d_ws, size_t ws_size,
                              hipStream_t stream) {
    const float* x   = (const float*)d_in[0];
    const int* ei    = (const int*)d_in[1];   // harness: integer -> int32
    const int* batch = (const int*)d_in[2];
    const float* W1a = (const float*)d_in[3];
    const float* b1a = (const float*)d_in[4];
    const float* W1b = (const float*)d_in[5];
    const float* b1b = (const float*)d_in[6];
    const float* g1  = (const float*)d_in[7];
    const float* be1 = (const float*)d_in[8];
    const float* W2a = (const float*)d_in[9];
    const float* b2a = (const float*)d_in[10];
    const float* W2b = (const float*)d_in[11];
    const float* b2b = (const float*)d_in[12];
    const float* g2  = (const float*)d_in[13];
    const float* be2 = (const float*)d_in[14];
    const float* Wo  = (const float*)d_in[15];
    const float* bo  = (const float*)d_in[16];

    char* ws = (char*)d_ws;
    const size_t NBH = (size_t)N_NODES * DIM * 2;   // 12.8 MB bf16 features
    unsigned short* xb   = (unsigned short*)ws;
    unsigned short* aggb = (unsigned short*)(ws + NBH);
    unsigned short* hb   = (unsigned short*)(ws + 2 * NBH);
    unsigned short* wfrag = (unsigned short*)(ws + 3 * NBH);   // 128 KB
    float* psum = (float*)(ws + 3 * NBH + 4 * 16384 * 2);      // NPART*128
    float* psq  = psum + (size_t)NPART * DIM;
    float* ps2  = psq + (size_t)NPART * DIM;       // RED_NB*256
    float* scale1  = ps2 + RED_NB * 256;
    float* shift1  = scale1 + 128;
    float* scale2  = scale1 + 256;
    float* shift2  = scale1 + 384;
    int* gs        = (int*)(shift2 + 128);         // N_GRAPHS+1
    int* gbcnt     = gs + N_GRAPHS + 1;            // NBUCK
    int* boff      = gbcnt + NBUCK;                // NBUCK+1
    int* gcur      = boff + NBUCK + 1;             // NBUCK
    int* row_start = gcur + NBUCK;                 // N_NODES+1
    unsigned* gbuf = (unsigned*)(row_start + N_NODES + 1);     // N_EDGES u32
    unsigned short* csr16 = (unsigned short*)(gbuf + N_EDGES); // N_EDGES ushort

    hipMemsetAsync(gbcnt, 0, NBUCK * 4, stream);

    prep_all<<<CVT_NB + PREPW_NB + FILL_NB + 1, 256, 0, stream>>>(
        (const f32x2*)x, (unsigned*)xb, W1a, W1b, W2a, W2b, wfrag, batch, gs, ei, gbcnt);

    bucket_scan<<<1, 256, 0, stream>>>(gbcnt, boff, gcur);
    bucket_fill<<<FILL_NB, 256, 0, stream>>>(ei, gcur, gbuf);
    csr_build<<<NBUCK, 256, 0, stream>>>(gbuf, boff, csr16, row_start);

    const int ablk = (N_NODES + 3) / 4;

    // layer 1
    aggregate_bf<false><<<ablk, 256, 0, stream>>>((const u32x4*)xb, (u32x4*)aggb,
                                                  row_start, csr16, nullptr, nullptr);
    fused_layer<<<FGRID, 256, 0, stream>>>(
        aggb, (const bf16x8*)(wfrag + 0 * 16384), (const bf16x8*)(wfrag + 1 * 16384),
        b1a, b1b, hb, psum, psq, N_NODES);
    reduce_stats<<<RED_NB, 256, 0, stream>>>(psum, psq, ps2);
    bn_finalize<<<1, 256, 0, stream>>>(ps2, g1, be1, scale1, shift1);

    // layer 2 (BN1+ReLU fused into aggregate)
    aggregate_bf<true><<<ablk, 256, 0, stream>>>((const u32x4*)hb, (u32x4*)aggb,
                                                 row_start, csr16, scale1, shift1);
    fused_layer<<<FGRID, 256, 0, stream>>>(
        aggb, (const bf16x8*)(wfrag + 2 * 16384), (const bf16x8*)(wfrag + 3 * 16384),
        b2a, b2b, hb, psum, psq, N_NODES);
    reduce_stats<<<RED_NB, 256, 0, stream>>>(psum, psq, ps2);
    bn_finalize<<<1, 256, 0, stream>>>(ps2, g2, be2, scale2, shift2);

    bn_pool_final<<<N_GRAPHS, 256, 0, stream>>>(hb, scale2, shift2, gs, Wo, bo,
                                                (float*)d_out);
}

// Round 18
// 224.799 us; speedup vs baseline: 1.0775x; 1.0097x over previous
//
#include <hip/hip_runtime.h>

typedef __attribute__((ext_vector_type(8))) short bf16x8;
typedef __attribute__((ext_vector_type(4))) float f32x4;
typedef __attribute__((ext_vector_type(2))) float f32x2;
typedef __attribute__((ext_vector_type(2))) unsigned u32x2;
typedef __attribute__((ext_vector_type(4))) unsigned u32x4;

#define N_NODES 50000
#define N_EDGES 800000
#define DIM 128
#define N_GRAPHS 128
#define N_CLASSES 10
#define BN_EPS 1e-5f
#define FBLK ((N_NODES + 63) / 64)        // 782 row tiles
#define FGRID (FBLK / 2)                  // 391 blocks, 2 tiles each
#define NPART (FBLK * 4)                  // 3128 stat-partial rows
#define RED_NB 64
#define RED_ROWS ((NPART + RED_NB - 1) / RED_NB)   // 49

#define NBUCK 196                         // dst buckets of 256 nodes
#define FILL_NB 400
#define FILL_PER (N_EDGES / FILL_NB)      // 2000
#define BMAX 6144                         // max bucket size

#define CVT_NB 2048                       // grid-stride conversion blocks
#define CVT_STRIDE (CVT_NB * 256)
#define PREPW_NB 256

static __device__ __forceinline__ unsigned short f2bf(float f) {
    unsigned u = __float_as_uint(f);
    u += 0x7FFF + ((u >> 16) & 1);   // round-to-nearest-even
    return (unsigned short)(u >> 16);
}
static __device__ __forceinline__ float bf_lo(unsigned u) { return __uint_as_float(u << 16); }
static __device__ __forceinline__ float bf_hi(unsigned u) { return __uint_as_float(u & 0xffff0000u); }
static __device__ __forceinline__ unsigned packbf(float a, float b) {
    return (unsigned)f2bf(a) | ((unsigned)f2bf(b) << 16);
}

// ---- fused prep: x->bf16 (grid-stride) | W permute | bucket_count | graph starts ----
__global__ __launch_bounds__(256) void prep_all(const f32x2* __restrict__ x,
                                                unsigned* __restrict__ xb,
                                                const float* __restrict__ W0,
                                                const float* __restrict__ W1,
                                                const float* __restrict__ W2,
                                                const float* __restrict__ W3,
                                                unsigned short* __restrict__ wf,
                                                const int* __restrict__ batch,
                                                int* __restrict__ gs,
                                                const int* __restrict__ ei,
                                                int* __restrict__ gbcnt) {
    int b = blockIdx.x, tid = threadIdx.x;
    if (b < CVT_NB) {
        const int nv2 = N_NODES * 64;   // f32x2 count
        for (int t = b * 256 + tid; t < nv2; t += CVT_STRIDE) {
            f32x2 v = x[t];
            xb[t] = packbf(v[0], v[1]);
        }
    } else if (b < CVT_NB + PREPW_NB) {
        int t = (b - CVT_NB) * 256 + tid;
        int m = t >> 14, rem = t & 16383;
        int e = rem & 7, lane = (rem >> 3) & 63, fi = rem >> 9;
        int ks = fi & 3, n = fi >> 2;
        int col = n * 16 + (lane & 15);
        int k = ks * 32 + ((lane >> 4) << 3) + e;
        const float* W = (m == 0) ? W0 : (m == 1) ? W1 : (m == 2) ? W2 : W3;
        wf[t] = f2bf(W[k * DIM + col]);
    } else if (b < CVT_NB + PREPW_NB + FILL_NB) {
        __shared__ int cnt[NBUCK];
        if (tid < NBUCK) cnt[tid] = 0;
        __syncthreads();
        int e0 = (b - CVT_NB - PREPW_NB) * FILL_PER;
        for (int c = tid; c < FILL_PER; c += 256) {
            int dst = ei[N_EDGES + e0 + c];
            atomicAdd(&cnt[dst >> 8], 1);
        }
        __syncthreads();
        if (tid < NBUCK) atomicAdd(&gbcnt[tid], cnt[tid]);
    } else {
        int g = tid;
        if (g > N_GRAPHS) return;
        int lo = 0, hi = N_NODES;
        while (lo < hi) {
            int mid = (lo + hi) >> 1;
            if (batch[mid] < g) lo = mid + 1; else hi = mid;
        }
        gs[g] = lo;
    }
}

// ---- CSR build stage 2: scan 196 bucket counts; init cursors ----
__global__ __launch_bounds__(256) void bucket_scan(const int* __restrict__ gbcnt,
                                                   int* __restrict__ boff,
                                                   int* __restrict__ gcur) {
    __shared__ int buf[256];
    int t = threadIdx.x;
    int v = (t < NBUCK) ? gbcnt[t] : 0;
    buf[t] = v;
    __syncthreads();
#pragma unroll
    for (int off = 1; off < 256; off <<= 1) {
        int u = (t >= off) ? buf[t - off] : 0;
        __syncthreads();
        buf[t] += u;
        __syncthreads();
    }
    if (t < NBUCK) { int ex = buf[t] - v; boff[t] = ex; gcur[t] = ex; }
    if (t == 0) boff[NBUCK] = N_EDGES;
}

// ---- CSR build stage 3: block-local counting sort by bucket ----
__global__ __launch_bounds__(256) void bucket_fill(const int* __restrict__ ei,
                                                   int* __restrict__ gcur,
                                                   unsigned* __restrict__ gbuf) {
    __shared__ unsigned ent[FILL_PER];
    __shared__ unsigned srt[FILL_PER];
    __shared__ int cnt[256], c2[256], lofs[256], gbase[256];
    int tid = threadIdx.x;
    int e0 = blockIdx.x * FILL_PER;
    cnt[tid] = 0; c2[tid] = 0;
    __syncthreads();
    for (int i = tid; i < FILL_PER; i += 256) {
        int src = ei[e0 + i];
        int dst = ei[N_EDGES + e0 + i];
        ent[i] = (unsigned)src | ((unsigned)(dst & 255) << 16) | ((unsigned)(dst >> 8) << 24);
        atomicAdd(&cnt[dst >> 8], 1);
    }
    __syncthreads();
    int v = cnt[tid];
    lofs[tid] = v;
    __syncthreads();
#pragma unroll
    for (int off = 1; off < 256; off <<= 1) {
        int u = (tid >= off) ? lofs[tid - off] : 0;
        __syncthreads();
        lofs[tid] += u;
        __syncthreads();
    }
    int excl = lofs[tid] - v;
    lofs[tid] = excl;
    if (tid < NBUCK && v > 0) gbase[tid] = atomicAdd(&gcur[tid], v);
    __syncthreads();
    for (int i = tid; i < FILL_PER; i += 256) {
        unsigned w = ent[i];
        int b = w >> 24;
        int r = atomicAdd(&c2[b], 1);
        srt[lofs[b] + r] = w;
    }
    __syncthreads();
    for (int i = tid; i < FILL_PER; i += 256) {
        unsigned w = srt[i];
        int b = w >> 24;
        gbuf[gbase[b] + (i - lofs[b])] = w;
    }
}

// ---- CSR build stage 4: per-bucket in-LDS sort -> row_start + ushort csr ----
__global__ __launch_bounds__(256) void csr_build(const unsigned* __restrict__ gbuf,
                                                 const int* __restrict__ boff,
                                                 unsigned short* __restrict__ csr16,
                                                 int* __restrict__ row_start) {
    __shared__ unsigned ent[BMAX];
    __shared__ unsigned short csl[BMAX];
    __shared__ int cnt[256], c2[256], offs[256];
    int b = blockIdx.x, t = threadIdx.x;
    int base = boff[b], n = boff[b + 1] - base;
    for (int i = t; i < n; i += 256) ent[i] = gbuf[base + i];
    cnt[t] = 0; c2[t] = 0;
    __syncthreads();
    for (int i = t; i < n; i += 256) atomicAdd(&cnt[(ent[i] >> 16) & 255], 1);
    __syncthreads();
    int v = cnt[t];
    offs[t] = v;
    __syncthreads();
#pragma unroll
    for (int off = 1; off < 256; off <<= 1) {
        int u = (t >= off) ? offs[t - off] : 0;
        __syncthreads();
        offs[t] += u;
        __syncthreads();
    }
    int excl = offs[t] - v;
    int node = b * 256 + t;
    if (node < N_NODES) row_start[node] = base + excl;
    if (b == NBUCK - 1 && t == 0) row_start[N_NODES] = N_EDGES;
    __syncthreads();
    offs[t] = excl;
    __syncthreads();
    for (int i = t; i < n; i += 256) {
        unsigned w = ent[i];
        int d = (w >> 16) & 255;
        int r = atomicAdd(&c2[d], 1);
        csl[offs[d] + r] = (unsigned short)(w & 0xffffu);
    }
    __syncthreads();
    for (int i = t; i < n; i += 256) csr16[base + i] = csl[i];
}

// ---- gather-sum aggregation: 16B/lane quarter-wave groups + 4-deep MLP ----
// (at its L2-miss service floor ~42us; structure frozen since r17)
template <bool BN>
__global__ __launch_bounds__(256) void aggregate_bf(const u32x4* __restrict__ F4,
                                                    u32x4* __restrict__ out,
                                                    const int* __restrict__ row_start,
                                                    const unsigned short* __restrict__ csr16,
                                                    const float* __restrict__ scale,
                                                    const float* __restrict__ shift) {
    int wave = threadIdx.x >> 6, lane = threadIdx.x & 63;
    int v = blockIdx.x * 4 + wave;
    if (v >= N_NODES) return;
    int q = lane >> 4;       // group 0..3
    int c8 = lane & 15;      // 16B chunk (8 cols) within row
    f32x4 scA, scB, shA, shB;
    if (BN) {
        scA = ((const f32x4*)scale)[c8 * 2];
        scB = ((const f32x4*)scale)[c8 * 2 + 1];
        shA = ((const f32x4*)shift)[c8 * 2];
        shB = ((const f32x4*)shift)[c8 * 2 + 1];
    }
    int e0 = row_start[v];
    int n = row_start[v + 1] - e0;
    int myidx = (lane < n) ? (int)csr16[e0 + lane] : 0;   // coalesced 2B/lane, 64 edges
    int n64 = (n < 64) ? n : 64;   // wave-uniform

    float a[8] = {0.f, 0.f, 0.f, 0.f, 0.f, 0.f, 0.f, 0.f};
    float b2[8] = {0.f, 0.f, 0.f, 0.f, 0.f, 0.f, 0.f, 0.f};

#define UNPACK8(U, P)                                                         \
    P[0] = bf_lo(U[0]); P[1] = bf_hi(U[0]); P[2] = bf_lo(U[1]); P[3] = bf_hi(U[1]); \
    P[4] = bf_lo(U[2]); P[5] = bf_hi(U[2]); P[6] = bf_lo(U[3]); P[7] = bf_hi(U[3]);
#define BN8(P)                                                                \
    if (BN) {                                                                 \
        P[0] = fmaxf(P[0] * scA[0] + shA[0], 0.f);                            \
        P[1] = fmaxf(P[1] * scA[1] + shA[1], 0.f);                            \
        P[2] = fmaxf(P[2] * scA[2] + shA[2], 0.f);                            \
        P[3] = fmaxf(P[3] * scA[3] + shA[3], 0.f);                            \
        P[4] = fmaxf(P[4] * scB[0] + shB[0], 0.f);                            \
        P[5] = fmaxf(P[5] * scB[1] + shB[1], 0.f);                            \
        P[6] = fmaxf(P[6] * scB[2] + shB[2], 0.f);                            \
        P[7] = fmaxf(P[7] * scB[3] + shB[3], 0.f);                            \
    }

    if (q == 0) {   // self term (group 0 only; counted once after combine)
        u32x4 u = F4[(size_t)v * 16 + c8];
        float p[8];
        UNPACK8(u, p)
        BN8(p)
#pragma unroll
        for (int k = 0; k < 8; ++k) a[k] += p[k];
    }

    for (int base = 0; base < n64; base += 16) {   // uniform trips; 4 loads in flight
        int j0 = base + q, j1 = base + 4 + q, j2 = base + 8 + q, j3 = base + 12 + q;
        int s0 = __shfl(myidx, j0 & 63, 64);
        int s1 = __shfl(myidx, j1 & 63, 64);
        int s2 = __shfl(myidx, j2 & 63, 64);
        int s3 = __shfl(myidx, j3 & 63, 64);
        u32x4 ua = F4[(size_t)s0 * 16 + c8];
        u32x4 ub = F4[(size_t)s1 * 16 + c8];
        u32x4 uc = F4[(size_t)s2 * 16 + c8];
        u32x4 ud = F4[(size_t)s3 * 16 + c8];
        float pa[8], pb[8], pc[8], pd[8];
        UNPACK8(ua, pa)
        UNPACK8(ub, pb)
        UNPACK8(uc, pc)
        UNPACK8(ud, pd)
        BN8(pa)
        BN8(pb)
        BN8(pc)
        BN8(pd)
        if (j0 < n64) {
#pragma unroll
            for (int k = 0; k < 8; ++k) a[k] += pa[k];
        }
        if (j1 < n64) {
#pragma unroll
            for (int k = 0; k < 8; ++k) b2[k] += pb[k];
        }
        if (j2 < n64) {
#pragma unroll
            for (int k = 0; k < 8; ++k) a[k] += pc[k];
        }
        if (j3 < n64) {
#pragma unroll
            for (int k = 0; k < 8; ++k) b2[k] += pd[k];
        }
    }
    for (int j = 64 + q; j < n; j += 4) {   // rare deg>64 tail: direct loads, no shfl
        int s = csr16[e0 + j];
        u32x4 ua = F4[(size_t)s * 16 + c8];
        float p[8];
        UNPACK8(ua, p)
        BN8(p)
#pragma unroll
        for (int k = 0; k < 8; ++k) a[k] += p[k];
    }
#pragma unroll
    for (int k = 0; k < 8; ++k) a[k] += b2[k];
    // combine the 4 groups (same columns, disjoint edges)
#pragma unroll
    for (int k = 0; k < 8; ++k) {
        a[k] += __shfl_xor(a[k], 16, 64);
        a[k] += __shfl_xor(a[k], 32, 64);
    }
    if (q == 0) {
        u32x4 w;
        w[0] = packbf(a[0], a[1]);
        w[1] = packbf(a[2], a[3]);
        w[2] = packbf(a[4], a[5]);
        w[3] = packbf(a[6], a[7]);
        out[(size_t)v * 16 + c8] = w;
    }
#undef UNPACK8
#undef BN8
}

// ---- fused GIN layer: 2 row-tiles per block; Wa+Wb in regs, staged per phase ----
__global__ __launch_bounds__(256, 3) void fused_layer(
        const unsigned short* __restrict__ A,
        const bf16x8* __restrict__ wfA_g,
        const bf16x8* __restrict__ wfB_g,
        const float* __restrict__ bias_a,
        const float* __restrict__ bias_b,
        unsigned short* __restrict__ out,
        float* __restrict__ psum,
        float* __restrict__ psq, int M) {
    __shared__ bf16x8 wfS[2048];
    __shared__ unsigned short mid[8192];

    int tid = threadIdx.x;
    int w = tid >> 6, lane = tid & 63;
    int cl = lane & 15, kq = lane >> 4;

    bf16x8 wa[8], wb[8];
#pragma unroll
    for (int i = 0; i < 8; ++i) wa[i] = wfA_g[i * 256 + tid];
#pragma unroll
    for (int i = 0; i < 8; ++i) wb[i] = wfB_g[i * 256 + tid];

    for (int t = 0; t < 2; ++t) {
        int tile = blockIdx.x + t * FGRID;
        int rblk = tile * 64;

#pragma unroll
        for (int i = 0; i < 8; ++i) wfS[i * 256 + tid] = wa[i];

        int arow = rblk + w * 16 + cl;
        if (arow >= M) arow = M - 1;
        bf16x8 af[4];
        const unsigned short* Ap = A + (size_t)arow * DIM + kq * 8;
#pragma unroll
        for (int ks = 0; ks < 4; ++ks) af[ks] = *(const bf16x8*)(Ap + ks * 32);

        __syncthreads();

        f32x4 acc[8];
#pragma unroll
        for (int n = 0; n < 8; ++n) acc[n] = f32x4{0.f, 0.f, 0.f, 0.f};
#pragma unroll
        for (int n = 0; n < 8; ++n)
#pragma unroll
            for (int ks = 0; ks < 4; ++ks)
                acc[n] = __builtin_amdgcn_mfma_f32_16x16x32_bf16(
                    af[ks], wfS[(n * 4 + ks) * 64 + lane], acc[n], 0, 0, 0);

#pragma unroll
        for (int n = 0; n < 8; ++n) {
            int col = n * 16 + cl;
            float b = bias_a[col];
#pragma unroll
            for (int r = 0; r < 4; ++r) {
                int rl = w * 16 + kq * 4 + r;
                float v = fmaxf(acc[n][r] + b, 0.f);
                mid[(rl * DIM + col) ^ ((rl & 7) << 3)] = f2bf(v);
            }
        }
        __syncthreads();

#pragma unroll
        for (int i = 0; i < 8; ++i) wfS[i * 256 + tid] = wb[i];

        bf16x8 af2[4];
        {
            int rl = w * 16 + cl;
            int sw = (cl & 7) << 3;
#pragma unroll
            for (int ks = 0; ks < 4; ++ks)
                af2[ks] = *(const bf16x8*)(mid + ((rl * DIM + kq * 8 + ks * 32) ^ sw));
        }
        __syncthreads();

        f32x4 acc2[8];
#pragma unroll
        for (int n = 0; n < 8; ++n) acc2[n] = f32x4{0.f, 0.f, 0.f, 0.f};
#pragma unroll
        for (int n = 0; n < 8; ++n)
#pragma unroll
            for (int ks = 0; ks < 4; ++ks)
                acc2[n] = __builtin_amdgcn_mfma_f32_16x16x32_bf16(
                    af2[ks], wfS[(n * 4 + ks) * 64 + lane], acc2[n], 0, 0, 0);

        int prow = tile * 4 + w;
#pragma unroll
        for (int n = 0; n < 8; ++n) {
            int col = n * 16 + cl;
            float b = bias_b[col];
            float s = 0.f, q = 0.f;
#pragma unroll
            for (int r = 0; r < 4; ++r) {
                int rl = w * 16 + kq * 4 + r;
                float v = acc2[n][r] + b;
                if (rblk + rl < M) { s += v; q += v * v; }
                mid[(rl * DIM + col) ^ ((rl & 7) << 3)] = f2bf(v);
            }
            s += __shfl_xor(s, 16, 64);
            s += __shfl_xor(s, 32, 64);
            q += __shfl_xor(q, 16, 64);
            q += __shfl_xor(q, 32, 64);
            if (kq == 0) {
                psum[(size_t)prow * DIM + col] = s;
                psq[(size_t)prow * DIM + col] = q;
            }
        }

        {
            int r4 = lane >> 4, c = lane & 15;
#pragma unroll
            for (int rb = 0; rb < 4; ++rb) {
                int rl = w * 16 + rb * 4 + r4;
                int grow = rblk + rl;
                bf16x8 v = *(const bf16x8*)(mid + ((rl * DIM + c * 8) ^ ((rl & 7) << 3)));
                if (grow < M) *(bf16x8*)(out + (size_t)grow * DIM + c * 8) = v;
            }
        }
        __syncthreads();
    }
}

// ---- stats reduction stage 1 ----
__global__ __launch_bounds__(256) void reduce_stats(const float* __restrict__ psum,
                                                    const float* __restrict__ psq,
                                                    float* __restrict__ ps2) {
    int b = blockIdx.x, t = threadIdx.x;
    int c = t & 127;
    const float* src = (t < 128) ? psum : psq;
    int r0 = b * RED_ROWS;
    int r1 = min(NPART, r0 + RED_ROWS);
    float acc = 0.f;
    for (int r = r0; r < r1; ++r) acc += src[(size_t)r * DIM + c];
    ps2[(size_t)b * 256 + t] = acc;
}

// ---- BN finalize ----
__global__ __launch_bounds__(256) void bn_finalize(const float* __restrict__ ps2,
                                                   const float* __restrict__ g,
                                                   const float* __restrict__ be,
                                                   float* __restrict__ scale,
                                                   float* __restrict__ shift) {
    __shared__ float sums[128], sqs[128];
    int t = threadIdx.x;
    int c = t & 127;
    float acc = 0.f;
#pragma unroll 4
    for (int r = 0; r < RED_NB; ++r) acc += ps2[(size_t)r * 256 + t];
    if (t < 128) sums[c] = acc; else sqs[c] = acc;
    __syncthreads();
    if (t < 128) {
        const float invN = 1.0f / (float)N_NODES;
        float mu = sums[c] * invN;
        float var = sqs[c] * invN - mu * mu;
        float rs = rsqrtf(var + BN_EPS) * g[c];
        scale[c] = rs;
        shift[c] = be[c] - mu * rs;
    }
}

// ---- BN apply + ReLU + segmented pool + classifier (one block per graph) ----
__global__ __launch_bounds__(256) void bn_pool_final(const unsigned short* __restrict__ h,
                                                     const float* __restrict__ scale,
                                                     const float* __restrict__ shift,
                                                     const int* __restrict__ gs,
                                                     const float* __restrict__ Wo,
                                                     const float* __restrict__ bo,
                                                     float* __restrict__ out) {
    int g = blockIdx.x;
    int t = threadIdx.x;
    int c4 = t & 31;
    int rs = t >> 5;
    int r0 = gs[g], r1 = gs[g + 1];
    f32x4 sc = ((const f32x4*)scale)[c4];
    f32x4 sh = ((const f32x4*)shift)[c4];
    f32x4 acc = f32x4{0.f, 0.f, 0.f, 0.f};
    for (int r = r0 + rs; r < r1; r += 8) {
        u32x2 u = *(const u32x2*)(h + (size_t)r * DIM + c4 * 4);
        float f0 = bf_lo(u[0]), f1 = bf_hi(u[0]), f2 = bf_lo(u[1]), f3 = bf_hi(u[1]);
        acc[0] += fmaxf(f0 * sc[0] + sh[0], 0.f);
        acc[1] += fmaxf(f1 * sc[1] + sh[1], 0.f);
        acc[2] += fmaxf(f2 * sc[2] + sh[2], 0.f);
        acc[3] += fmaxf(f3 * sc[3] + sh[3], 0.f);
    }
    __shared__ f32x4 red[256];
    __shared__ float pf[DIM];
    red[t] = acc;
    __syncthreads();
#pragma unroll
    for (int off = 128; off >= 32; off >>= 1) {
        if (t < off) red[t] += red[t + off];
        __syncthreads();
    }
    if (t < 32) {
        f32x4 r = red[t];
        pf[t * 4 + 0] = r[0]; pf[t * 4 + 1] = r[1];
        pf[t * 4 + 2] = r[2]; pf[t * 4 + 3] = r[3];
    }
    __syncthreads();
    if (t < N_CLASSES) {
        float s = bo[t];
#pragma unroll 8
        for (int k = 0; k < DIM; ++k) s += pf[k] * Wo[k * N_CLASSES + t];
        out[g * N_CLASSES + t] = s;
    }
}

extern "C" void kernel_launch(void* const* d_in, const int* in_sizes, int n_in,
                              void* d_out, int out_size, void* d_ws, size_t ws_size,
                              hipStream_t stream) {
    const float* x   = (const float*)d_in[0];
    const int* ei    = (const int*)d_in[1];   // harness: integer -> int32
    const int* batch = (const int*)d_in[2];
    const float* W1a = (const float*)d_in[3];
    const float* b1a = (const float*)d_in[4];
    const float* W1b = (const float*)d_in[5];
    const float* b1b = (const float*)d_in[6];
    const float* g1  = (const float*)d_in[7];
    const float* be1 = (const float*)d_in[8];
    const float* W2a = (const float*)d_in[9];
    const float* b2a = (const float*)d_in[10];
    const float* W2b = (const float*)d_in[11];
    const float* b2b = (const float*)d_in[12];
    const float* g2  = (const float*)d_in[13];
    const float* be2 = (const float*)d_in[14];
    const float* Wo  = (const float*)d_in[15];
    const float* bo  = (const float*)d_in[16];

    char* ws = (char*)d_ws;
    const size_t NBH = (size_t)N_NODES * DIM * 2;   // 12.8 MB bf16 features
    unsigned short* xb   = (unsigned short*)ws;
    unsigned short* aggb = (unsigned short*)(ws + NBH);
    unsigned short* hb   = (unsigned short*)(ws + 2 * NBH);
    unsigned short* wfrag = (unsigned short*)(ws + 3 * NBH);   // 128 KB
    float* psum = (float*)(ws + 3 * NBH + 4 * 16384 * 2);      // NPART*128
    float* psq  = psum + (size_t)NPART * DIM;
    float* ps2  = psq + (size_t)NPART * DIM;       // RED_NB*256
    float* scale1  = ps2 + RED_NB * 256;
    float* shift1  = scale1 + 128;
    float* scale2  = scale1 + 256;
    float* shift2  = scale1 + 384;
    int* gs        = (int*)(shift2 + 128);         // N_GRAPHS+1
    int* gbcnt     = gs + N_GRAPHS + 1;            // NBUCK
    int* boff      = gbcnt + NBUCK;                // NBUCK+1
    int* gcur      = boff + NBUCK + 1;             // NBUCK
    int* row_start = gcur + NBUCK;                 // N_NODES+1
    unsigned* gbuf = (unsigned*)(row_start + N_NODES + 1);     // N_EDGES u32
    unsigned short* csr16 = (unsigned short*)(gbuf + N_EDGES); // N_EDGES ushort

    hipMemsetAsync(gbcnt, 0, NBUCK * 4, stream);

    prep_all<<<CVT_NB + PREPW_NB + FILL_NB + 1, 256, 0, stream>>>(
        (const f32x2*)x, (unsigned*)xb, W1a, W1b, W2a, W2b, wfrag, batch, gs, ei, gbcnt);

    bucket_scan<<<1, 256, 0, stream>>>(gbcnt, boff, gcur);
    bucket_fill<<<FILL_NB, 256, 0, stream>>>(ei, gcur, gbuf);
    csr_build<<<NBUCK, 256, 0, stream>>>(gbuf, boff, csr16, row_start);

    const int ablk = (N_NODES + 3) / 4;

    // layer 1
    aggregate_bf<false><<<ablk, 256, 0, stream>>>((const u32x4*)xb, (u32x4*)aggb,
                                                  row_start, csr16, nullptr, nullptr);
    fused_layer<<<FGRID, 256, 0, stream>>>(
        aggb, (const bf16x8*)(wfrag + 0 * 16384), (const bf16x8*)(wfrag + 1 * 16384),
        b1a, b1b, hb, psum, psq, N_NODES);
    reduce_stats<<<RED_NB, 256, 0, stream>>>(psum, psq, ps2);
    bn_finalize<<<1, 256, 0, stream>>>(ps2, g1, be1, scale1, shift1);

    // layer 2 (BN1+ReLU fused into aggregate)
    aggregate_bf<true><<<ablk, 256, 0, stream>>>((const u32x4*)hb, (u32x4*)aggb,
                                                 row_start, csr16, scale1, shift1);
    fused_layer<<<FGRID, 256, 0, stream>>>(
        aggb, (const bf16x8*)(wfrag + 2 * 16384), (const bf16x8*)(wfrag + 3 * 16384),
        b2a, b2b, hb, psum, psq, N_NODES);
    reduce_stats<<<RED_NB, 256, 0, stream>>>(psum, psq, ps2);
    bn_finalize<<<1, 256, 0, stream>>>(ps2, g2, be2, scale2, shift2);

    bn_pool_final<<<N_GRAPHS, 256, 0, stream>>>(hb, scale2, shift2, gs, Wo, bo,
                                                (float*)d_out);
}

// Round 19
// 218.793 us; speedup vs baseline: 1.1071x; 1.0275x over previous
//
#include <hip/hip_runtime.h>

typedef __attribute__((ext_vector_type(8))) short bf16x8;
typedef __attribute__((ext_vector_type(4))) float f32x4;
typedef __attribute__((ext_vector_type(2))) float f32x2;
typedef __attribute__((ext_vector_type(2))) unsigned u32x2;

#define N_NODES 50000
#define N_EDGES 800000
#define DIM 128
#define N_GRAPHS 128
#define N_CLASSES 10
#define BN_EPS 1e-5f
#define FBLK ((N_NODES + 63) / 64)        // 782 row tiles
#define FGRID (FBLK / 2)                  // 391 blocks, 2 tiles each
#define NPART (FBLK * 4)                  // 3128 stat-partial rows
#define RED_NB 64
#define RED_ROWS ((NPART + RED_NB - 1) / RED_NB)   // 49

#define NBUCK 196                         // dst buckets of 256 nodes
#define FILL_NB 400
#define FILL_PER (N_EDGES / FILL_NB)      // 2000
#define BMAX 6144                         // max bucket size

#define CVT_NB 2048                       // grid-stride conversion blocks
#define CVT_STRIDE (CVT_NB * 256)
#define PREPW_NB 256

static __device__ __forceinline__ unsigned short f2bf(float f) {
    unsigned u = __float_as_uint(f);
    u += 0x7FFF + ((u >> 16) & 1);   // round-to-nearest-even
    return (unsigned short)(u >> 16);
}
static __device__ __forceinline__ float bf_lo(unsigned u) { return __uint_as_float(u << 16); }
static __device__ __forceinline__ float bf_hi(unsigned u) { return __uint_as_float(u & 0xffff0000u); }
static __device__ __forceinline__ unsigned packbf(float a, float b) {
    return (unsigned)f2bf(a) | ((unsigned)f2bf(b) << 16);
}

// ---- fused prep: x->bf16 (grid-stride) | W permute | bucket_count | graph starts ----
__global__ __launch_bounds__(256) void prep_all(const f32x2* __restrict__ x,
                                                unsigned* __restrict__ xb,
                                                const float* __restrict__ W0,
                                                const float* __restrict__ W1,
                                                const float* __restrict__ W2,
                                                const float* __restrict__ W3,
                                                unsigned short* __restrict__ wf,
                                                const int* __restrict__ batch,
                                                int* __restrict__ gs,
                                                const int* __restrict__ ei,
                                                int* __restrict__ gbcnt) {
    int b = blockIdx.x, tid = threadIdx.x;
    if (b < CVT_NB) {
        const int nv2 = N_NODES * 64;   // f32x2 count
        for (int t = b * 256 + tid; t < nv2; t += CVT_STRIDE) {
            f32x2 v = x[t];
            xb[t] = packbf(v[0], v[1]);
        }
    } else if (b < CVT_NB + PREPW_NB) {
        int t = (b - CVT_NB) * 256 + tid;
        int m = t >> 14, rem = t & 16383;
        int e = rem & 7, lane = (rem >> 3) & 63, fi = rem >> 9;
        int ks = fi & 3, n = fi >> 2;
        int col = n * 16 + (lane & 15);
        int k = ks * 32 + ((lane >> 4) << 3) + e;
        const float* W = (m == 0) ? W0 : (m == 1) ? W1 : (m == 2) ? W2 : W3;
        wf[t] = f2bf(W[k * DIM + col]);
    } else if (b < CVT_NB + PREPW_NB + FILL_NB) {
        __shared__ int cnt[NBUCK];
        if (tid < NBUCK) cnt[tid] = 0;
        __syncthreads();
        int e0 = (b - CVT_NB - PREPW_NB) * FILL_PER;
        for (int c = tid; c < FILL_PER; c += 256) {
            int dst = ei[N_EDGES + e0 + c];
            atomicAdd(&cnt[dst >> 8], 1);
        }
        __syncthreads();
        if (tid < NBUCK) atomicAdd(&gbcnt[tid], cnt[tid]);
    } else {
        int g = tid;
        if (g > N_GRAPHS) return;
        int lo = 0, hi = N_NODES;
        while (lo < hi) {
            int mid = (lo + hi) >> 1;
            if (batch[mid] < g) lo = mid + 1; else hi = mid;
        }
        gs[g] = lo;
    }
}

// ---- CSR build stage 2: scan 196 bucket counts; init cursors ----
__global__ __launch_bounds__(256) void bucket_scan(const int* __restrict__ gbcnt,
                                                   int* __restrict__ boff,
                                                   int* __restrict__ gcur) {
    __shared__ int buf[256];
    int t = threadIdx.x;
    int v = (t < NBUCK) ? gbcnt[t] : 0;
    buf[t] = v;
    __syncthreads();
#pragma unroll
    for (int off = 1; off < 256; off <<= 1) {
        int u = (t >= off) ? buf[t - off] : 0;
        __syncthreads();
        buf[t] += u;
        __syncthreads();
    }
    if (t < NBUCK) { int ex = buf[t] - v; boff[t] = ex; gcur[t] = ex; }
    if (t == 0) boff[NBUCK] = N_EDGES;
}

// ---- CSR build stage 3: block-local counting sort by bucket ----
__global__ __launch_bounds__(256) void bucket_fill(const int* __restrict__ ei,
                                                   int* __restrict__ gcur,
                                                   unsigned* __restrict__ gbuf) {
    __shared__ unsigned ent[FILL_PER];
    __shared__ unsigned srt[FILL_PER];
    __shared__ int cnt[256], c2[256], lofs[256], gbase[256];
    int tid = threadIdx.x;
    int e0 = blockIdx.x * FILL_PER;
    cnt[tid] = 0; c2[tid] = 0;
    __syncthreads();
    for (int i = tid; i < FILL_PER; i += 256) {
        int src = ei[e0 + i];
        int dst = ei[N_EDGES + e0 + i];
        ent[i] = (unsigned)src | ((unsigned)(dst & 255) << 16) | ((unsigned)(dst >> 8) << 24);
        atomicAdd(&cnt[dst >> 8], 1);
    }
    __syncthreads();
    int v = cnt[tid];
    lofs[tid] = v;
    __syncthreads();
#pragma unroll
    for (int off = 1; off < 256; off <<= 1) {
        int u = (tid >= off) ? lofs[tid - off] : 0;
        __syncthreads();
        lofs[tid] += u;
        __syncthreads();
    }
    int excl = lofs[tid] - v;
    lofs[tid] = excl;
    if (tid < NBUCK && v > 0) gbase[tid] = atomicAdd(&gcur[tid], v);
    __syncthreads();
    for (int i = tid; i < FILL_PER; i += 256) {
        unsigned w = ent[i];
        int b = w >> 24;
        int r = atomicAdd(&c2[b], 1);
        srt[lofs[b] + r] = w;
    }
    __syncthreads();
    for (int i = tid; i < FILL_PER; i += 256) {
        unsigned w = srt[i];
        int b = w >> 24;
        gbuf[gbase[b] + (i - lofs[b])] = w;
    }
}

// ---- CSR build stage 4: per-bucket in-LDS sort -> row_start + ushort csr ----
__global__ __launch_bounds__(256) void csr_build(const unsigned* __restrict__ gbuf,
                                                 const int* __restrict__ boff,
                                                 unsigned short* __restrict__ csr16,
                                                 int* __restrict__ row_start) {
    __shared__ unsigned ent[BMAX];
    __shared__ unsigned short csl[BMAX];
    __shared__ int cnt[256], c2[256], offs[256];
    int b = blockIdx.x, t = threadIdx.x;
    int base = boff[b], n = boff[b + 1] - base;
    for (int i = t; i < n; i += 256) ent[i] = gbuf[base + i];
    cnt[t] = 0; c2[t] = 0;
    __syncthreads();
    for (int i = t; i < n; i += 256) atomicAdd(&cnt[(ent[i] >> 16) & 255], 1);
    __syncthreads();
    int v = cnt[t];
    offs[t] = v;
    __syncthreads();
#pragma unroll
    for (int off = 1; off < 256; off <<= 1) {
        int u = (t >= off) ? offs[t - off] : 0;
        __syncthreads();
        offs[t] += u;
        __syncthreads();
    }
    int excl = offs[t] - v;
    int node = b * 256 + t;
    if (node < N_NODES) row_start[node] = base + excl;
    if (b == NBUCK - 1 && t == 0) row_start[N_NODES] = N_EDGES;
    __syncthreads();
    offs[t] = excl;
    __syncthreads();
    for (int i = t; i < n; i += 256) {
        unsigned w = ent[i];
        int d = (w >> 16) & 255;
        int r = atomicAdd(&c2[d], 1);
        csl[offs[d] + r] = (unsigned short)(w & 0xffffu);
    }
    __syncthreads();
    for (int i = t; i < n; i += 256) csr16[base + i] = csl[i];
}

// ---- gather-sum aggregation: 8B/lane half-waves, 4-deep MLP, uniform loop ----
// (r15 best-measured variant; VGPR 20; half 0: even edges (+self); half 1: odd)
template <bool BN>
__global__ __launch_bounds__(256) void aggregate_bf(const u32x2* __restrict__ F2,
                                                    u32x2* __restrict__ out,
                                                    const int* __restrict__ row_start,
                                                    const unsigned short* __restrict__ csr16,
                                                    const float* __restrict__ scale,
                                                    const float* __restrict__ shift) {
    int wave = threadIdx.x >> 6, lane = threadIdx.x & 63;
    int v = blockIdx.x * 4 + wave;
    if (v >= N_NODES) return;
    int half = lane >> 5;
    int c4 = lane & 31;
    f32x4 sc, sh;
    if (BN) {
        sc = ((const f32x4*)scale)[c4];
        sh = ((const f32x4*)shift)[c4];
    }
    int e0 = row_start[v];
    int n = row_start[v + 1] - e0;
    int myidx = (lane < n) ? (int)csr16[e0 + lane] : 0;
    int n64 = (n < 64) ? n : 64;   // wave-uniform

    f32x4 a0 = f32x4{0.f, 0.f, 0.f, 0.f};
    f32x4 a1 = f32x4{0.f, 0.f, 0.f, 0.f};
    if (half == 0) {   // self term
        u32x2 u = F2[(size_t)v * 32 + c4];
        a0[0] = bf_lo(u[0]); a0[1] = bf_hi(u[0]);
        a0[2] = bf_lo(u[1]); a0[3] = bf_hi(u[1]);
        if (BN) {
#pragma unroll
            for (int k = 0; k < 4; ++k) a0[k] = fmaxf(a0[k] * sc[k] + sh[k], 0.f);
        }
    }

    for (int base = 0; base < n64; base += 8) {   // uniform trip count, safe shfl
        int j0 = base + half, j1 = j0 + 2, j2 = j0 + 4, j3 = j0 + 6;
        int s0 = __shfl(myidx, j0 & 63, 64);
        int s1 = __shfl(myidx, j1 & 63, 64);
        int s2 = __shfl(myidx, j2 & 63, 64);
        int s3 = __shfl(myidx, j3 & 63, 64);
        u32x2 ua = F2[(size_t)s0 * 32 + c4];
        u32x2 ub = F2[(size_t)s1 * 32 + c4];
        u32x2 uc = F2[(size_t)s2 * 32 + c4];
        u32x2 ud = F2[(size_t)s3 * 32 + c4];
        float p0 = bf_lo(ua[0]), p1 = bf_hi(ua[0]), p2 = bf_lo(ua[1]), p3 = bf_hi(ua[1]);
        float q0 = bf_lo(ub[0]), q1 = bf_hi(ub[0]), q2 = bf_lo(ub[1]), q3 = bf_hi(ub[1]);
        float r0 = bf_lo(uc[0]), r1 = bf_hi(uc[0]), r2 = bf_lo(uc[1]), r3 = bf_hi(uc[1]);
        float t0 = bf_lo(ud[0]), t1 = bf_hi(ud[0]), t2 = bf_lo(ud[1]), t3 = bf_hi(ud[1]);
        if (BN) {
            p0 = fmaxf(p0 * sc[0] + sh[0], 0.f); p1 = fmaxf(p1 * sc[1] + sh[1], 0.f);
            p2 = fmaxf(p2 * sc[2] + sh[2], 0.f); p3 = fmaxf(p3 * sc[3] + sh[3], 0.f);
            q0 = fmaxf(q0 * sc[0] + sh[0], 0.f); q1 = fmaxf(q1 * sc[1] + sh[1], 0.f);
            q2 = fmaxf(q2 * sc[2] + sh[2], 0.f); q3 = fmaxf(q3 * sc[3] + sh[3], 0.f);
            r0 = fmaxf(r0 * sc[0] + sh[0], 0.f); r1 = fmaxf(r1 * sc[1] + sh[1], 0.f);
            r2 = fmaxf(r2 * sc[2] + sh[2], 0.f); r3 = fmaxf(r3 * sc[3] + sh[3], 0.f);
            t0 = fmaxf(t0 * sc[0] + sh[0], 0.f); t1 = fmaxf(t1 * sc[1] + sh[1], 0.f);
            t2 = fmaxf(t2 * sc[2] + sh[2], 0.f); t3 = fmaxf(t3 * sc[3] + sh[3], 0.f);
        }
        if (j0 < n64) { a0[0] += p0; a0[1] += p1; a0[2] += p2; a0[3] += p3; }
        if (j1 < n64) { a0[0] += q0; a0[1] += q1; a0[2] += q2; a0[3] += q3; }
        if (j2 < n64) { a1[0] += r0; a1[1] += r1; a1[2] += r2; a1[3] += r3; }
        if (j3 < n64) { a1[0] += t0; a1[1] += t1; a1[2] += t2; a1[3] += t3; }
    }
    for (int j = 64 + half; j < n; j += 2) {   // rare: degree > 64 (no shfl)
        int s = csr16[e0 + j];
        u32x2 ua = F2[(size_t)s * 32 + c4];
        float p0 = bf_lo(ua[0]), p1 = bf_hi(ua[0]), p2 = bf_lo(ua[1]), p3 = bf_hi(ua[1]);
        if (BN) {
            p0 = fmaxf(p0 * sc[0] + sh[0], 0.f); p1 = fmaxf(p1 * sc[1] + sh[1], 0.f);
            p2 = fmaxf(p2 * sc[2] + sh[2], 0.f); p3 = fmaxf(p3 * sc[3] + sh[3], 0.f);
        }
        a0[0] += p0; a0[1] += p1; a0[2] += p2; a0[3] += p3;
    }
#pragma unroll
    for (int k = 0; k < 4; ++k) a0[k] += a1[k];
#pragma unroll
    for (int k = 0; k < 4; ++k) a0[k] += __shfl_xor(a0[k], 32, 64);
    if (half == 0) {
        u32x2 w;
        w[0] = packbf(a0[0], a0[1]);
        w[1] = packbf(a0[2], a0[3]);
        out[(size_t)v * 32 + c4] = w;
    }
}

// ---- fused GIN layer: 2 row-tiles per block; Wa+Wb in regs, staged per phase ----
__global__ __launch_bounds__(256, 3) void fused_layer(
        const unsigned short* __restrict__ A,
        const bf16x8* __restrict__ wfA_g,
        const bf16x8* __restrict__ wfB_g,
        const float* __restrict__ bias_a,
        const float* __restrict__ bias_b,
        unsigned short* __restrict__ out,
        float* __restrict__ psum,
        float* __restrict__ psq, int M) {
    __shared__ bf16x8 wfS[2048];
    __shared__ unsigned short mid[8192];

    int tid = threadIdx.x;
    int w = tid >> 6, lane = tid & 63;
    int cl = lane & 15, kq = lane >> 4;

    bf16x8 wa[8], wb[8];
#pragma unroll
    for (int i = 0; i < 8; ++i) wa[i] = wfA_g[i * 256 + tid];
#pragma unroll
    for (int i = 0; i < 8; ++i) wb[i] = wfB_g[i * 256 + tid];

    for (int t = 0; t < 2; ++t) {
        int tile = blockIdx.x + t * FGRID;
        int rblk = tile * 64;

#pragma unroll
        for (int i = 0; i < 8; ++i) wfS[i * 256 + tid] = wa[i];

        int arow = rblk + w * 16 + cl;
        if (arow >= M) arow = M - 1;
        bf16x8 af[4];
        const unsigned short* Ap = A + (size_t)arow * DIM + kq * 8;
#pragma unroll
        for (int ks = 0; ks < 4; ++ks) af[ks] = *(const bf16x8*)(Ap + ks * 32);

        __syncthreads();

        f32x4 acc[8];
#pragma unroll
        for (int n = 0; n < 8; ++n) acc[n] = f32x4{0.f, 0.f, 0.f, 0.f};
#pragma unroll
        for (int n = 0; n < 8; ++n)
#pragma unroll
            for (int ks = 0; ks < 4; ++ks)
                acc[n] = __builtin_amdgcn_mfma_f32_16x16x32_bf16(
                    af[ks], wfS[(n * 4 + ks) * 64 + lane], acc[n], 0, 0, 0);

#pragma unroll
        for (int n = 0; n < 8; ++n) {
            int col = n * 16 + cl;
            float b = bias_a[col];
#pragma unroll
            for (int r = 0; r < 4; ++r) {
                int rl = w * 16 + kq * 4 + r;
                float v = fmaxf(acc[n][r] + b, 0.f);
                mid[(rl * DIM + col) ^ ((rl & 7) << 3)] = f2bf(v);
            }
        }
        __syncthreads();

#pragma unroll
        for (int i = 0; i < 8; ++i) wfS[i * 256 + tid] = wb[i];

        bf16x8 af2[4];
        {
            int rl = w * 16 + cl;
            int sw = (cl & 7) << 3;
#pragma unroll
            for (int ks = 0; ks < 4; ++ks)
                af2[ks] = *(const bf16x8*)(mid + ((rl * DIM + kq * 8 + ks * 32) ^ sw));
        }
        __syncthreads();

        f32x4 acc2[8];
#pragma unroll
        for (int n = 0; n < 8; ++n) acc2[n] = f32x4{0.f, 0.f, 0.f, 0.f};
#pragma unroll
        for (int n = 0; n < 8; ++n)
#pragma unroll
            for (int ks = 0; ks < 4; ++ks)
                acc2[n] = __builtin_amdgcn_mfma_f32_16x16x32_bf16(
                    af2[ks], wfS[(n * 4 + ks) * 64 + lane], acc2[n], 0, 0, 0);

        int prow = tile * 4 + w;
#pragma unroll
        for (int n = 0; n < 8; ++n) {
            int col = n * 16 + cl;
            float b = bias_b[col];
            float s = 0.f, q = 0.f;
#pragma unroll
            for (int r = 0; r < 4; ++r) {
                int rl = w * 16 + kq * 4 + r;
                float v = acc2[n][r] + b;
                if (rblk + rl < M) { s += v; q += v * v; }
                mid[(rl * DIM + col) ^ ((rl & 7) << 3)] = f2bf(v);
            }
            s += __shfl_xor(s, 16, 64);
            s += __shfl_xor(s, 32, 64);
            q += __shfl_xor(q, 16, 64);
            q += __shfl_xor(q, 32, 64);
            if (kq == 0) {
                psum[(size_t)prow * DIM + col] = s;
                psq[(size_t)prow * DIM + col] = q;
            }
        }

        {
            int r4 = lane >> 4, c = lane & 15;
#pragma unroll
            for (int rb = 0; rb < 4; ++rb) {
                int rl = w * 16 + rb * 4 + r4;
                int grow = rblk + rl;
                bf16x8 v = *(const bf16x8*)(mid + ((rl * DIM + c * 8) ^ ((rl & 7) << 3)));
                if (grow < M) *(bf16x8*)(out + (size_t)grow * DIM + c * 8) = v;
            }
        }
        __syncthreads();
    }
}

// ---- stats reduction stage 1 ----
__global__ __launch_bounds__(256) void reduce_stats(const float* __restrict__ psum,
                                                    const float* __restrict__ psq,
                                                    float* __restrict__ ps2) {
    int b = blockIdx.x, t = threadIdx.x;
    int c = t & 127;
    const float* src = (t < 128) ? psum : psq;
    int r0 = b * RED_ROWS;
    int r1 = min(NPART, r0 + RED_ROWS);
    float acc = 0.f;
    for (int r = r0; r < r1; ++r) acc += src[(size_t)r * DIM + c];
    ps2[(size_t)b * 256 + t] = acc;
}

// ---- BN finalize ----
__global__ __launch_bounds__(256) void bn_finalize(const float* __restrict__ ps2,
                                                   const float* __restrict__ g,
                                                   const float* __restrict__ be,
                                                   float* __restrict__ scale,
                                                   float* __restrict__ shift) {
    __shared__ float sums[128], sqs[128];
    int t = threadIdx.x;
    int c = t & 127;
    float acc = 0.f;
#pragma unroll 4
    for (int r = 0; r < RED_NB; ++r) acc += ps2[(size_t)r * 256 + t];
    if (t < 128) sums[c] = acc; else sqs[c] = acc;
    __syncthreads();
    if (t < 128) {
        const float invN = 1.0f / (float)N_NODES;
        float mu = sums[c] * invN;
        float var = sqs[c] * invN - mu * mu;
        float rs = rsqrtf(var + BN_EPS) * g[c];
        scale[c] = rs;
        shift[c] = be[c] - mu * rs;
    }
}

// ---- BN apply + ReLU + segmented pool + classifier (one block per graph) ----
__global__ __launch_bounds__(256) void bn_pool_final(const unsigned short* __restrict__ h,
                                                     const float* __restrict__ scale,
                                                     const float* __restrict__ shift,
                                                     const int* __restrict__ gs,
                                                     const float* __restrict__ Wo,
                                                     const float* __restrict__ bo,
                                                     float* __restrict__ out) {
    int g = blockIdx.x;
    int t = threadIdx.x;
    int c4 = t & 31;
    int rs = t >> 5;
    int r0 = gs[g], r1 = gs[g + 1];
    f32x4 sc = ((const f32x4*)scale)[c4];
    f32x4 sh = ((const f32x4*)shift)[c4];
    f32x4 acc = f32x4{0.f, 0.f, 0.f, 0.f};
    for (int r = r0 + rs; r < r1; r += 8) {
        u32x2 u = *(const u32x2*)(h + (size_t)r * DIM + c4 * 4);
        float f0 = bf_lo(u[0]), f1 = bf_hi(u[0]), f2 = bf_lo(u[1]), f3 = bf_hi(u[1]);
        acc[0] += fmaxf(f0 * sc[0] + sh[0], 0.f);
        acc[1] += fmaxf(f1 * sc[1] + sh[1], 0.f);
        acc[2] += fmaxf(f2 * sc[2] + sh[2], 0.f);
        acc[3] += fmaxf(f3 * sc[3] + sh[3], 0.f);
    }
    __shared__ f32x4 red[256];
    __shared__ float pf[DIM];
    red[t] = acc;
    __syncthreads();
#pragma unroll
    for (int off = 128; off >= 32; off >>= 1) {
        if (t < off) red[t] += red[t + off];
        __syncthreads();
    }
    if (t < 32) {
        f32x4 r = red[t];
        pf[t * 4 + 0] = r[0]; pf[t * 4 + 1] = r[1];
        pf[t * 4 + 2] = r[2]; pf[t * 4 + 3] = r[3];
    }
    __syncthreads();
    if (t < N_CLASSES) {
        float s = bo[t];
#pragma unroll 8
        for (int k = 0; k < DIM; ++k) s += pf[k] * Wo[k * N_CLASSES + t];
        out[g * N_CLASSES + t] = s;
    }
}

extern "C" void kernel_launch(void* const* d_in, const int* in_sizes, int n_in,
                              void* d_out, int out_size, void* d_ws, size_t ws_size,
                              hipStream_t stream) {
    const float* x   = (const float*)d_in[0];
    const int* ei    = (const int*)d_in[1];   // harness: integer -> int32
    const int* batch = (const int*)d_in[2];
    const float* W1a = (const float*)d_in[3];
    const float* b1a = (const float*)d_in[4];
    const float* W1b = (const float*)d_in[5];
    const float* b1b = (const float*)d_in[6];
    const float* g1  = (const float*)d_in[7];
    const float* be1 = (const float*)d_in[8];
    const float* W2a = (const float*)d_in[9];
    const float* b2a = (const float*)d_in[10];
    const float* W2b = (const float*)d_in[11];
    const float* b2b = (const float*)d_in[12];
    const float* g2  = (const float*)d_in[13];
    const float* be2 = (const float*)d_in[14];
    const float* Wo  = (const float*)d_in[15];
    const float* bo  = (const float*)d_in[16];

    char* ws = (char*)d_ws;
    const size_t NBH = (size_t)N_NODES * DIM * 2;   // 12.8 MB bf16 features
    unsigned short* xb   = (unsigned short*)ws;
    unsigned short* aggb = (unsigned short*)(ws + NBH);
    unsigned short* hb   = (unsigned short*)(ws + 2 * NBH);
    unsigned short* wfrag = (unsigned short*)(ws + 3 * NBH);   // 128 KB
    float* psum = (float*)(ws + 3 * NBH + 4 * 16384 * 2);      // NPART*128
    float* psq  = psum + (size_t)NPART * DIM;
    float* ps2  = psq + (size_t)NPART * DIM;       // RED_NB*256
    float* scale1  = ps2 + RED_NB * 256;
    float* shift1  = scale1 + 128;
    float* scale2  = scale1 + 256;
    float* shift2  = scale1 + 384;
    int* gs        = (int*)(shift2 + 128);         // N_GRAPHS+1
    int* gbcnt     = gs + N_GRAPHS + 1;            // NBUCK
    int* boff      = gbcnt + NBUCK;                // NBUCK+1
    int* gcur      = boff + NBUCK + 1;             // NBUCK
    int* row_start = gcur + NBUCK;                 // N_NODES+1
    unsigned* gbuf = (unsigned*)(row_start + N_NODES + 1);     // N_EDGES u32
    unsigned short* csr16 = (unsigned short*)(gbuf + N_EDGES); // N_EDGES ushort

    hipMemsetAsync(gbcnt, 0, NBUCK * 4, stream);

    prep_all<<<CVT_NB + PREPW_NB + FILL_NB + 1, 256, 0, stream>>>(
        (const f32x2*)x, (unsigned*)xb, W1a, W1b, W2a, W2b, wfrag, batch, gs, ei, gbcnt);

    bucket_scan<<<1, 256, 0, stream>>>(gbcnt, boff, gcur);
    bucket_fill<<<FILL_NB, 256, 0, stream>>>(ei, gcur, gbuf);
    csr_build<<<NBUCK, 256, 0, stream>>>(gbuf, boff, csr16, row_start);

    const int ablk = (N_NODES + 3) / 4;

    // layer 1
    aggregate_bf<false><<<ablk, 256, 0, stream>>>((const u32x2*)xb, (u32x2*)aggb,
                                                  row_start, csr16, nullptr, nullptr);
    fused_layer<<<FGRID, 256, 0, stream>>>(
        aggb, (const bf16x8*)(wfrag + 0 * 16384), (const bf16x8*)(wfrag + 1 * 16384),
        b1a, b1b, hb, psum, psq, N_NODES);
    reduce_stats<<<RED_NB, 256, 0, stream>>>(psum, psq, ps2);
    bn_finalize<<<1, 256, 0, stream>>>(ps2, g1, be1, scale1, shift1);

    // layer 2 (BN1+ReLU fused into aggregate)
    aggregate_bf<true><<<ablk, 256, 0, stream>>>((const u32x2*)hb, (u32x2*)aggb,
                                                 row_start, csr16, scale1, shift1);
    fused_layer<<<FGRID, 256, 0, stream>>>(
        aggb, (const bf16x8*)(wfrag + 2 * 16384), (const bf16x8*)(wfrag + 3 * 16384),
        b2a, b2b, hb, psum, psq, N_NODES);
    reduce_stats<<<RED_NB, 256, 0, stream>>>(psum, psq, ps2);
    bn_finalize<<<1, 256, 0, stream>>>(ps2, g2, be2, scale2, shift2);

    bn_pool_final<<<N_GRAPHS, 256, 0, stream>>>(hb, scale2, shift2, gs, Wo, bo,
                                                (float*)d_out);
}